// Round 8
// baseline (1346.171 us; speedup 1.0000x reference)
//
#include <hip/hip_runtime.h>

typedef __attribute__((ext_vector_type(8))) short short8;
typedef __attribute__((ext_vector_type(4))) float f32x4;
typedef unsigned short u16;
typedef unsigned long long u64;

__device__ __forceinline__ unsigned short f2bf(float f) {
  union { float f; unsigned u; } v; v.f = f;
  unsigned r = v.u + 0x7fffu + ((v.u >> 16) & 1u);
  return (unsigned short)(r >> 16);
}
__device__ __forceinline__ unsigned pack2bf(float lo, float hi) {
  return (unsigned)f2bf(lo) | ((unsigned)f2bf(hi) << 16);
}
__device__ __forceinline__ float sigm(float x) { return 1.0f / (1.0f + __expf(-x)); }
__device__ __forceinline__ float tanh_fast(float x) { return 1.0f - 2.0f / (__expf(2.0f * x) + 1.0f); }

// relaxed agent-scope (coherent-point) helpers: bypass L1/L2, NO cache flush.
__device__ __forceinline__ void st64coh(u64* p, u64 v) {
  __hip_atomic_store(p, v, __ATOMIC_RELAXED, __HIP_MEMORY_SCOPE_AGENT);
}
__device__ __forceinline__ u64 ld64coh(const u64* p) {
  return __hip_atomic_load(p, __ATOMIC_RELAXED, __HIP_MEMORY_SCOPE_AGENT);
}
__device__ __forceinline__ u64 packf2(float a, float b) {
  union { float f[2]; u64 u; } t; t.f[0] = a; t.f[1] = b; return t.u;
}

// ---------- fp32 -> bf16 convert + pack into MFMA-fragment order ----------
// packed blob: [tile16][kstep32][lane64][8]; lane = (row&15) + 16*((k>>3)&3).
// Plain stores (dense 16B). In-kernel rides rely on the one-time L2
// writeback fence at the encoder->decoder transition for cross-XCD visibility.
__device__ __forceinline__ void cvt_body(const float* __restrict__ src,
                                         uint4* __restrict__ dst,
                                         int lb, int ns, int klog,
                                         u16 (*lds)[1032]) {
  int ht = lb / ns, span = lb - ht * ns;
  long row0 = (long)ht * 8;
  int c0 = span << 10;

  const int tr = threadIdx.x >> 5, tc = threadIdx.x & 31;
  const float* srow = src + ((row0 + tr) << klog) + c0;
#pragma unroll
  for (int p = 0; p < 8; ++p) {
    int col = p * 128 + tc * 4;
    float4 v = *(const float4*)(srow + col);
    *(uint2*)&lds[tr][col] = make_uint2(pack2bf(v.x, v.y), pack2bf(v.z, v.w));
  }
  __syncthreads();
  int tile = ht >> 1, h0 = (ht & 1) * 8;
  long ks = 1l << (klog - 5);
  uint4* dbase = dst + ((long)tile * ks + span * 32) * 64 + h0;
#pragma unroll
  for (int i = 0; i < 4; ++i) {
    int ci = threadIdx.x + 256 * i;
    int rr = ci & 7, kgrp = (ci >> 3) & 3, kstep = ci >> 5;
    dbase[(long)kstep * 64 + rr + 16 * kgrp] = *(const uint4*)&lds[rr][kstep * 32 + kgrp * 8];
  }
}

#define NPK 12
struct PKArgs {
  const float* src[NPK];
  uint4* dst[NPK];
  int cum[NPK + 1];
  int nspan[NPK];
  int klog[NPK];
};

__global__ __launch_bounds__(256) void cvt_pack(PKArgs a) {
  __shared__ __align__(16) u16 lds[8][1032];
  int b = blockIdx.x;
  int r = 0;
  while (b >= a.cum[r + 1]) ++r;
  cvt_body(a.src[r], a.dst[r], b - a.cum[r], a.nspan[r], a.klog[r], lds);
}

// ---------- pipelined dual-mtile K-segment: 4-kstep groups, double-buffered ----
// PLAIN cached loads. Safe: every A (h-state) buffer is per-timestep private,
// written once via coherent (L2-bypass) store BEFORE its first cached read.
__device__ __forceinline__ void seg_mm(
    const short8* __restrict__ ap, const short8* __restrict__ wp, int ks,
    int sb, int se, f32x4& acc0, f32x4& acc1)
{
  if (sb >= se) return;
  short8 xa0[4], xb0[4], wv0[4], xa1[4], xb1[4], wv1[4];
#define LDG(B, S) { _Pragma("unroll") for (int d = 0; d < 4; ++d) { \
    xa##B[d] = ap[(long)((S) + d) * 64]; \
    xb##B[d] = ap[(long)(ks + (S) + d) * 64]; \
    wv##B[d] = wp[(long)((S) + d) * 64]; } }
#define MMG(B) { _Pragma("unroll") for (int d = 0; d < 4; ++d) { \
    acc0 = __builtin_amdgcn_mfma_f32_16x16x32_bf16(xa##B[d], wv##B[d], acc0, 0, 0, 0); \
    acc1 = __builtin_amdgcn_mfma_f32_16x16x32_bf16(xb##B[d], wv##B[d], acc1, 0, 0, 0); } }
  int s = sb;
  const int ng = (se - sb) >> 2;
  LDG(0, s)
  for (int g = 0; g < ng; g += 2) {
    LDG(1, s + 4)
    __builtin_amdgcn_sched_barrier(0);
    MMG(0)
    if (g + 2 < ng) LDG(0, s + 8)
    __builtin_amdgcn_sched_barrier(0);
    MMG(1)
    s += 8;
  }
#undef LDG
#undef MMG
}

// ---------- xpre = X (SBxK packed) @ W (NxK packed)^T, fp32 out ----------
__global__ __launch_bounds__(256) void gemm_pre(
    const u16* __restrict__ A, const u16* __restrict__ W,
    float* __restrict__ C, int N, int K)
{
  const int ks = K >> 5;
  const int m0 = blockIdx.x * 64;
  const int n0 = blockIdx.y * 64;
  const int w = threadIdx.x >> 6;
  const int lane = threadIdx.x & 63;
  const int colr = lane & 15;
  const int kgrp = lane >> 4;
  f32x4 acc[4] = {{0.f,0.f,0.f,0.f},{0.f,0.f,0.f,0.f},{0.f,0.f,0.f,0.f},{0.f,0.f,0.f,0.f}};
  const short8* ap = (const short8*)A + (long)(m0 / 16 + w) * ks * 64 + lane;
  const short8* wp = (const short8*)W + (long)(n0 / 16) * ks * 64 + lane;
  short8 av0[2], bv0[8], av1[2], bv1[8];
#define LDP(B, S) { _Pragma("unroll") for (int d = 0; d < 2; ++d) { \
    av##B[d] = ap[(long)((S) + d) * 64]; \
    _Pragma("unroll") for (int ct = 0; ct < 4; ++ct) \
      bv##B[ct * 2 + d] = wp[((long)ct * ks + (S) + d) * 64]; } }
#define MMP(B) { _Pragma("unroll") for (int d = 0; d < 2; ++d) \
    _Pragma("unroll") for (int ct = 0; ct < 4; ++ct) \
      acc[ct] = __builtin_amdgcn_mfma_f32_16x16x32_bf16(av##B[d], bv##B[ct * 2 + d], acc[ct], 0, 0, 0); }
  LDP(0, 0)
  for (int s = 0; s < ks; s += 4) {
    LDP(1, s + 2)
    __builtin_amdgcn_sched_barrier(0);
    MMP(0)
    if (s + 4 < ks) LDP(0, s + 4)
    __builtin_amdgcn_sched_barrier(0);
    MMP(1)
  }
#undef LDP
#undef MMP
#pragma unroll
  for (int ct = 0; ct < 4; ++ct)
#pragma unroll
    for (int j = 0; j < 4; ++j)
      C[(long)(m0 + w * 16 + kgrp * 4 + j) * N + n0 + ct * 16 + colr] = acc[ct][j];
}

// ---------- persistent fused LSTM sequence kernel ----------
struct Cell {
  const u16 *A1, *W1, *A2, *W2;
  const float *pre, *bias;
  float *cbuf; u16 *hout; float *sigout;
  float *part; int *cnt;
  int K1, K2, dh, chunk, nslog, blkend;
};

struct SeqParams {
  const u16* wb[11];
  const float* bias6[6];
  u16 *eh0, *eh1, *eh2;     // per-timestep private h: base + t*32*H (u16)
  u16 *dh0, *dh1;
  u16 *dh2;                 // stride 32*D
  float* ec[3];
  float* dc3[3];
  const float* xpre;
  float* part; int* cnt;
  float* outp;
  int S, FUT, H, D, nstage, ride_per, rtot;
  const float* rsrc[5]; uint4* rdst[5];
  int rcum[6], rns[5], rklog[5];
  int* bar;   // tree: leaf i at bar[i*16] (i<32), root bar[512], phase bar[528]
};

// Flush-free grid barrier: monotonic relaxed agent atomics, 32-leaf tree.
// 512 blocks @ __launch_bounds__(256,2) = 2 blocks/CU co-resident on 256 CUs.
__device__ __forceinline__ void grid_sync(int* bar, int nblk, int& lphase) {
  __syncthreads();
  if (threadIdx.x == 0) {
    ++lphase;
    const int NL = 32;
    const int per = nblk / NL;
    const int leaf = (int)blockIdx.x & (NL - 1);
    int t = __hip_atomic_fetch_add(&bar[leaf * 16], 1, __ATOMIC_RELAXED, __HIP_MEMORY_SCOPE_AGENT);
    if (t == lphase * per - 1) {
      int r = __hip_atomic_fetch_add(&bar[NL * 16], 1, __ATOMIC_RELAXED, __HIP_MEMORY_SCOPE_AGENT);
      if (r == lphase * NL - 1)
        __hip_atomic_store(&bar[NL * 16 + 16], lphase, __ATOMIC_RELAXED, __HIP_MEMORY_SCOPE_AGENT);
    }
    while (__hip_atomic_load(&bar[NL * 16 + 16], __ATOMIC_RELAXED, __HIP_MEMORY_SCOPE_AGENT) < lphase)
      __builtin_amdgcn_s_sleep(2);
  }
  __syncthreads();
}

// Work decomposition (grid=512):
//   encoder stages: c1/c2/c3 nslog=1 -> 384 items, one round.
//   decoder stages: CELL3 FIRST with nslog=1 (512 items -> ALL 512 blocks
//   stream the 168MB weight set in parallel, 8 waves/CU), then c1/c2
//   (nslog=1, 128 each, L2/L3-resident) as second items on blocks 0..255.
__device__ int build_stage(const SeqParams& p, int st, Cell c[3]) {
  const int H = p.H, D = p.D;
  const long sH = (long)32 * H;
  const long sD = (long)32 * D;
  const long PARTSTRIDE = (long)256 * 8 * 4 * 512;
  int blk = 0, nc = 0;
  auto add = [&](const u16* A1, const u16* W1, int K1,
                 const u16* A2, const u16* W2, int K2,
                 const float* pre, const float* bs, float* cb, u16* ho,
                 float* so, int dh, int nslog, int pi) {
    Cell& cd = c[nc];
    cd.A1 = A1; cd.W1 = W1; cd.K1 = K1;
    cd.A2 = A2; cd.W2 = W2; cd.K2 = K2;
    cd.pre = pre; cd.bias = bs;
    cd.cbuf = cb; cd.hout = ho; cd.sigout = so;
    cd.part = p.part + (long)pi * PARTSTRIDE;
    cd.cnt = p.cnt + pi * 256;
    cd.dh = dh; cd.nslog = nslog;
    cd.chunk = (K1 + K2) >> nslog;
    blk += (dh / 16) << nslog;
    cd.blkend = blk;
    ++nc;
  };
  if (st < p.S + 2) {
    int d = st, t = d;
    if (t < p.S)
      add(p.eh0 + t * sH, p.wb[1], H, nullptr, nullptr, 0,
          p.xpre + (long)t * 32 * 4 * H, p.bias6[0],
          p.ec[0], p.eh0 + (t + 1) * sH, nullptr, H, 1, 0);
    t = d - 1;
    if (t >= 0 && t < p.S)
      add(p.eh0 + (t + 1) * sH, p.wb[2], H, p.eh1 + t * sH, p.wb[3], H,
          nullptr, p.bias6[1], p.ec[1], p.eh1 + (t + 1) * sH, nullptr,
          H, 1, 1);
    t = d - 2;
    if (t >= 0 && t < p.S)
      add(p.eh1 + (t + 1) * sH, p.wb[4], H, p.eh2 + t * sH, p.wb[5], H,
          nullptr, p.bias6[2], p.ec[2], p.eh2 + (t + 1) * sH, nullptr,
          H, 1, 2);
  } else {
    int d = st - (p.S + 2), t;
    // cell3 first: max streaming parallelism on the 168MB/step weight set
    t = d - 2;
    if (t >= 0 && t < p.FUT)
      add(p.dh1 + (t + 1) * sH, p.wb[9], H, p.dh2 + t * sD, p.wb[10], D,
          nullptr, p.bias6[5], p.dc3[2], p.dh2 + (t + 1) * sD,
          p.outp + (long)t * 32 * D, D, 1, 2);
    t = d;
    if (t < p.FUT) {
      const u16* hprev = (t == 0) ? (p.eh2 + p.S * sH) : (p.dh0 + t * sH);
      add(hprev, p.wb[6], H, nullptr, nullptr, 0,
          nullptr, p.bias6[3], p.dc3[0], p.dh0 + (t + 1) * sH, nullptr,
          H, 1, 0);
    }
    t = d - 1;
    if (t >= 0 && t < p.FUT)
      add(p.dh0 + (t + 1) * sH, p.wb[7], H, p.dh1 + t * sH, p.wb[8], H,
          nullptr, p.bias6[4], p.dc3[1], p.dh1 + (t + 1) * sH, nullptr,
          H, 1, 1);
  }
  return blk;
}

__device__ void lstm_item(const Cell& cd, int local, void* smemraw, int* swinp) {
  const int nslog = cd.nslog;
  const int nsplit = 1 << nslog;
  const int tile = local >> nslog;
  const int split = local & (nsplit - 1);
  const int g = threadIdx.x >> 6;
  const int lane = threadIdx.x & 63;
  const int colr = lane & 15;
  const int kgrp = lane >> 4;
  const int dh = cd.dh;
  const int dh16 = dh >> 4;
  const int K1 = cd.K1, K2 = cd.K2;

  f32x4 acc0 = {0.f, 0.f, 0.f, 0.f};
  f32x4 acc1 = {0.f, 0.f, 0.f, 0.f};
  const int kbeg = split * cd.chunk;
  const int kend = kbeg + cd.chunk;

  if (kbeg < K1) {
    const int e = kend < K1 ? kend : K1;
    const int ks = K1 >> 5;
    seg_mm((const short8*)cd.A1 + lane,
           (const short8*)cd.W1 + (long)(g * dh16 + tile) * ks * 64 + lane,
           ks, kbeg >> 5, e >> 5, acc0, acc1);
  }
  if (kend > K1 && K2 > 0) {
    const int b0 = kbeg > K1 ? kbeg : K1;
    const int ks = K2 >> 5;
    seg_mm((const short8*)cd.A2 + lane,
           (const short8*)cd.W2 + (long)(g * dh16 + tile) * ks * 64 + lane,
           ks, (b0 - K1) >> 5, (kend - K1) >> 5, acc0, acc1);
  }

  if (nsplit > 1) {
    // split-K partials, plane-major [j][lane]: each st64coh/ld64coh
    // instruction covers a DENSE 512B run (64 lanes x 8B) -> no sector waste.
    u64* base = (u64*)(cd.part + ((long)((tile << nslog) + split) * 4 + g) * 512);
    st64coh(base + 0 * 64 + lane, packf2(acc0[0], acc0[1]));
    st64coh(base + 1 * 64 + lane, packf2(acc0[2], acc0[3]));
    st64coh(base + 2 * 64 + lane, packf2(acc1[0], acc1[1]));
    st64coh(base + 3 * 64 + lane, packf2(acc1[2], acc1[3]));
    __threadfence_block();
    __syncthreads();
    if (threadIdx.x == 0)
      *swinp = (atomicAdd(&cd.cnt[tile], 1) == nsplit - 1) ? 1 : 0;
    __syncthreads();
    if (!*swinp) return;
    __threadfence_block();
    for (int os = 0; os < nsplit; ++os) {
      if (os == split) continue;
      const u64* obase = (const u64*)(cd.part + ((long)((tile << nslog) + os) * 4 + g) * 512);
      u64 q0 = ld64coh(obase + 0 * 64 + lane);
      u64 q1 = ld64coh(obase + 1 * 64 + lane);
      u64 q2 = ld64coh(obase + 2 * 64 + lane);
      u64 q3 = ld64coh(obase + 3 * 64 + lane);
      union { u64 u; float f[2]; } t;
      t.u = q0; acc0[0] += t.f[0]; acc0[1] += t.f[1];
      t.u = q1; acc0[2] += t.f[0]; acc0[3] += t.f[1];
      t.u = q2; acc1[0] += t.f[0]; acc1[1] += t.f[1];
      t.u = q3; acc1[2] += t.f[0]; acc1[3] += t.f[1];
    }
    if (threadIdx.x == 0)
      __hip_atomic_store(&cd.cnt[tile], 0, __ATOMIC_RELAXED, __HIP_MEMORY_SCOPE_AGENT);
  }

  float (*ldsG)[16][33] = (float (*)[16][33])smemraw;
#pragma unroll
  for (int j = 0; j < 4; ++j) {
    ldsG[g][colr][kgrp * 4 + j] = acc0[j];
    ldsG[g][colr][16 + kgrp * 4 + j] = acc1[j];
  }
  __syncthreads();

  if (threadIdx.x < 64) {
    const int b2 = threadIdx.x >> 1;
    const int half = threadIdx.x & 1;
    const int u0l = half * 8;
    const int u0 = tile * 16 + u0l;
    // c-state address is reused every stage -> coherent path (small)
    const u64* crd = (const u64*)(cd.cbuf + (long)b2 * dh + u0);
    u64 cw[4];
#pragma unroll
    for (int q = 0; q < 4; ++q) cw[q] = ld64coh(crd + q);
    float hv[8], cv[8], sv[8];
#pragma unroll
    for (int e = 0; e < 8; ++e) {
      int ul = u0l + e;
      int u = tile * 16 + ul;
      float gi = ldsG[0][ul][b2] + cd.bias[u];
      float gf = ldsG[1][ul][b2] + cd.bias[dh + u];
      float gg = ldsG[2][ul][b2] + cd.bias[2 * dh + u];
      float go = ldsG[3][ul][b2] + cd.bias[3 * dh + u];
      if (cd.pre) {
        const float* pb = cd.pre + (long)b2 * 4 * dh;
        gi += pb[u]; gf += pb[dh + u]; gg += pb[2 * dh + u]; go += pb[3 * dh + u];
      }
      union { u64 q; float f[2]; } cu; cu.q = cw[e >> 1];
      float cold = cu.f[e & 1];
      float cn = sigm(gf) * cold + sigm(gi) * tanh_fast(gg);
      cv[e] = cn;
      float h = sigm(go) * tanh_fast(cn);
      hv[e] = h;
      sv[e] = sigm(h);
    }
    u64* cwr = (u64*)(cd.cbuf + (long)b2 * dh + u0);
#pragma unroll
    for (int q = 0; q < 4; ++q)
      st64coh(cwr + q, packf2(cv[2 * q], cv[2 * q + 1]));
    const int ksh = dh >> 5;
    const int mt = b2 >> 4;
    const int kstep = u0 >> 5;
    const int lanep = (b2 & 15) + 16 * ((u0 >> 3) & 3);
    uint4 hp;
    hp.x = pack2bf(hv[0], hv[1]); hp.y = pack2bf(hv[2], hv[3]);
    hp.z = pack2bf(hv[4], hv[5]); hp.w = pack2bf(hv[6], hv[7]);
    // h published via coherent store (L2-bypass); next stage reads it CACHED
    u64* hq = (u64*)&((uint4*)cd.hout)[((long)mt * ksh + kstep) * 64 + lanep];
    st64coh(hq,     (u64)hp.x | ((u64)hp.y << 32));
    st64coh(hq + 1, (u64)hp.z | ((u64)hp.w << 32));
    if (cd.sigout) {
      float4* sp = (float4*)(cd.sigout + (long)b2 * dh + u0);
      sp[0] = make_float4(sv[0], sv[1], sv[2], sv[3]);
      sp[1] = make_float4(sv[4], sv[5], sv[6], sv[7]);
    }
  }
}

__global__ __launch_bounds__(256, 2) void lstm_seq(SeqParams p) {
  __shared__ __align__(16) char smem[16512];   // union: cvt lds (16512B) / ldsG (8448B)
  __shared__ int swin;
  int lphase = 0;

  for (int st = 0; st < p.nstage; ++st) {
    Cell cells[3];
    const int nl = build_stage(p, st, cells);
    int rs = 0, rc = 0;
    if (st < p.S + 2) {
      rs = st * p.ride_per;
      rc = p.rtot - rs;
      if (rc < 0) rc = 0;
      if (rc > p.ride_per) rc = p.ride_per;
    }
    const int total = nl + rc;
    for (int it = blockIdx.x; it < total; it += (int)gridDim.x) {
      __syncthreads();                 // LDS reuse guard between items
      if (it < nl) {
        int ci = 0, bstart = 0;
        while (it >= cells[ci].blkend) { bstart = cells[ci].blkend; ++ci; }
        lstm_item(cells[ci], it - bstart, (void*)smem, &swin);
      } else {
        int pb = it - nl + rs;
        int r = 0;
        while (pb >= p.rcum[r + 1]) ++r;
        cvt_body(p.rsrc[r], p.rdst[r], pb - p.rcum[r], p.rns[r], p.rklog[r],
                 (u16 (*)[1032])smem);
      }
    }
    // One-time L2 writeback at the encoder->decoder transition publishes the
    // ride-converted decoder weights (plain stores) to HBM for all XCDs.
    if (st == p.S + 1) {
      __syncthreads();
      if (threadIdx.x == 0) __threadfence();
    }
    if (st + 1 < p.nstage) grid_sync(p.bar, (int)gridDim.x, lphase);
  }
}

// ------------------------------- host -----------------------------------------
extern "C" void kernel_launch(void* const* d_in, const int* in_sizes, int n_in,
                              void* d_out, int out_size, void* d_ws, size_t ws_size,
                              hipStream_t stream)
{
  const float* x_f = (const float*)d_in[0];
  const float* Wih[6]; const float* Whh[6]; const float* bias[6];
  for (int c = 0; c < 6; ++c) {
    Wih[c]  = (const float*)d_in[2 + 3 * c];
    Whh[c]  = (const float*)d_in[3 + 3 * c];
    bias[c] = (const float*)d_in[4 + 3 * c];
  }
  const int H = in_sizes[4] / 4;          // 1024
  const int D = in_sizes[2] / (4 * H);    // 4096
  const int B = 32;
  const int SB = in_sizes[0] / D;         // 640
  const int S = SB / B;                   // 20
  const int FUT = out_size / (B * D);     // 10
  (void)n_in; (void)ws_size;
  int klogH = 31 - __builtin_clz((unsigned)H);
  int klogD = 31 - __builtin_clz((unsigned)D);

  char* wsp = (char*)d_ws;
  size_t off = 0;
  auto alloc = [&](size_t bytes) -> void* {
    off = (off + 255) & ~(size_t)255;
    void* p = (void*)(wsp + off);
    off += bytes;
    return p;
  };

  const float* wsrc[11] = { Wih[0], Whh[0], Wih[1], Whh[1], Wih[2], Whh[2],
                            Whh[3], Wih[4], Whh[4], Wih[5], Whh[5] };
  long welems[11] = { (long)4*H*D, (long)4*H*H, (long)4*H*H, (long)4*H*H,
                      (long)4*H*H, (long)4*H*H, (long)4*H*H, (long)4*H*H,
                      (long)4*H*H, (long)4*D*H, (long)4*D*(long)D };
  int wrows[11] = { 4*H, 4*H, 4*H, 4*H, 4*H, 4*H, 4*H, 4*H, 4*H, 4*D, 4*D };
  int wklog[11] = { klogD, klogH, klogH, klogH, klogH, klogH,
                    klogH, klogH, klogH, klogH, klogD };
  u16* wb[11];
  for (int i = 0; i < 11; ++i) wb[i] = (u16*)alloc((size_t)welems[i] * 2);
  u16* xbf = (u16*)alloc((size_t)SB * D * 2);
  float* xpre = (float*)alloc((size_t)SB * D * 4);

  size_t zbeg = (off + 255) & ~(size_t)255;
  int* cnt = (int*)alloc(3 * 256 * 4);
  int* gbar = (int*)alloc(8192);
  const long sH = (long)B * H;            // u16 elems per h slot
  const long sD = (long)B * D;
  u16* eh0 = (u16*)alloc((size_t)(S + 1) * sH * 2);
  u16* eh1 = (u16*)alloc((size_t)(S + 1) * sH * 2);
  u16* eh2 = (u16*)alloc((size_t)(S + 1) * sH * 2);
  u16* dh0 = (u16*)alloc((size_t)(FUT + 1) * sH * 2);
  u16* dh1 = (u16*)alloc((size_t)(FUT + 1) * sH * 2);
  u16* dh2 = (u16*)alloc((size_t)(FUT + 1) * sD * 2);
  float* ec[3]; float* dc[3];
  for (int c = 0; c < 3; ++c) ec[c] = (float*)alloc((size_t)B * H * 4);
  dc[0] = (float*)alloc((size_t)B * H * 4);
  dc[1] = (float*)alloc((size_t)B * H * 4);
  dc[2] = (float*)alloc((size_t)B * D * 4);
  size_t zend = off;

  const long PARTSTRIDE = (long)256 * 8 * 4 * 512;   // floats per cell slot region
  float* part = (float*)alloc((size_t)3 * PARTSTRIDE * 4);

  hipMemsetAsync((void*)(wsp + zbeg), 0, zend - zbeg, stream);

  // ---- upfront conversion: encoder weights (wsrc[0..5]) + x ----
  PKArgs pa;
  int cum = 0;
  for (int i = 0; i < 7; ++i) {
    int rows, klog;
    if (i < 6) { rows = wrows[i]; klog = wklog[i]; pa.src[i] = wsrc[i]; pa.dst[i] = (uint4*)wb[i]; }
    else       { rows = SB;       klog = klogD;    pa.src[i] = x_f;     pa.dst[i] = (uint4*)xbf; }
    int ns = 1 << (klog - 10);
    pa.cum[i] = cum;
    pa.nspan[i] = ns;
    pa.klog[i] = klog;
    cum += (rows / 8) * ns;
  }
  for (int i = 7; i <= NPK; ++i) pa.cum[i] = cum;
  cvt_pack<<<dim3(cum), dim3(256), 0, stream>>>(pa);

  gemm_pre<<<dim3(SB / 64, (4 * H) / 64), dim3(256), 0, stream>>>(xbf, wb[0], xpre, 4 * H, D);

  // ---- persistent sequence kernel: all 34 LSTM stages + decoder-weight cvt rides ----
  SeqParams sp;
  for (int i = 0; i < 11; ++i) sp.wb[i] = wb[i];
  for (int i = 0; i < 6; ++i) sp.bias6[i] = bias[i];
  sp.eh0 = eh0; sp.eh1 = eh1; sp.eh2 = eh2;
  sp.dh0 = dh0; sp.dh1 = dh1; sp.dh2 = dh2;
  for (int c = 0; c < 3; ++c) { sp.ec[c] = ec[c]; sp.dc3[c] = dc[c]; }
  sp.xpre = xpre; sp.part = part; sp.cnt = cnt;
  sp.outp = (float*)d_out;
  sp.S = S; sp.FUT = FUT; sp.H = H; sp.D = D;
  sp.nstage = (S + 2) + (FUT + 2);
  int rcum = 0;
  for (int i = 0; i < 5; ++i) {
    int wi = 6 + i;
    sp.rsrc[i] = wsrc[wi];
    sp.rdst[i] = (uint4*)wb[wi];
    int ns = 1 << (wklog[wi] - 10);
    sp.rcum[i] = rcum;
    sp.rns[i] = ns;
    sp.rklog[i] = wklog[wi];
    rcum += (wrows[wi] / 8) * ns;
  }
  sp.rcum[5] = rcum;
  sp.rtot = rcum;
  sp.ride_per = (rcum + (S + 2) - 1) / (S + 2);
  sp.bar = gbar;

  lstm_seq<<<dim3(512), dim3(256), 0, stream>>>(sp);
}

// Round 9
// 1209.730 us; speedup vs baseline: 1.1128x; 1.1128x over previous
//
#include <hip/hip_runtime.h>

typedef __attribute__((ext_vector_type(8))) short short8;
typedef __attribute__((ext_vector_type(4))) float f32x4;
typedef unsigned short u16;
typedef unsigned long long u64;

__device__ __forceinline__ unsigned short f2bf(float f) {
  union { float f; unsigned u; } v; v.f = f;
  unsigned r = v.u + 0x7fffu + ((v.u >> 16) & 1u);
  return (unsigned short)(r >> 16);
}
__device__ __forceinline__ unsigned pack2bf(float lo, float hi) {
  return (unsigned)f2bf(lo) | ((unsigned)f2bf(hi) << 16);
}
__device__ __forceinline__ float sigm(float x) { return 1.0f / (1.0f + __expf(-x)); }
__device__ __forceinline__ float tanh_fast(float x) { return 1.0f - 2.0f / (__expf(2.0f * x) + 1.0f); }

// relaxed agent-scope (coherent-point) helpers: bypass L1/L2, NO cache flush.
__device__ __forceinline__ void st64coh(u64* p, u64 v) {
  __hip_atomic_store(p, v, __ATOMIC_RELAXED, __HIP_MEMORY_SCOPE_AGENT);
}
__device__ __forceinline__ u64 ld64coh(const u64* p) {
  return __hip_atomic_load(p, __ATOMIC_RELAXED, __HIP_MEMORY_SCOPE_AGENT);
}
__device__ __forceinline__ u64 packf2(float a, float b) {
  union { float f[2]; u64 u; } t; t.f[0] = a; t.f[1] = b; return t.u;
}

// ---------- fp32 -> bf16 convert + pack into MFMA-fragment order ----------
// packed blob: [tile16][kstep32][lane64][8]; lane = (row&15) + 16*((k>>3)&3).
// Plain stores (dense 16B). Ride conversions run in the ENCODER dispatch;
// the encoder->decoder kernel boundary provides the writeback/invalidate
// that publishes them to all XCDs for the decoder dispatch.
__device__ __forceinline__ void cvt_body(const float* __restrict__ src,
                                         uint4* __restrict__ dst,
                                         int lb, int ns, int klog,
                                         u16 (*lds)[1032]) {
  int ht = lb / ns, span = lb - ht * ns;
  long row0 = (long)ht * 8;
  int c0 = span << 10;

  const int tr = threadIdx.x >> 5, tc = threadIdx.x & 31;
  const float* srow = src + ((row0 + tr) << klog) + c0;
#pragma unroll
  for (int p = 0; p < 8; ++p) {
    int col = p * 128 + tc * 4;
    float4 v = *(const float4*)(srow + col);
    *(uint2*)&lds[tr][col] = make_uint2(pack2bf(v.x, v.y), pack2bf(v.z, v.w));
  }
  __syncthreads();
  int tile = ht >> 1, h0 = (ht & 1) * 8;
  long ks = 1l << (klog - 5);
  uint4* dbase = dst + ((long)tile * ks + span * 32) * 64 + h0;
#pragma unroll
  for (int i = 0; i < 4; ++i) {
    int ci = threadIdx.x + 256 * i;
    int rr = ci & 7, kgrp = (ci >> 3) & 3, kstep = ci >> 5;
    dbase[(long)kstep * 64 + rr + 16 * kgrp] = *(const uint4*)&lds[rr][kstep * 32 + kgrp * 8];
  }
}

#define NPK 12
struct PKArgs {
  const float* src[NPK];
  uint4* dst[NPK];
  int cum[NPK + 1];
  int nspan[NPK];
  int klog[NPK];
};

__global__ __launch_bounds__(256) void cvt_pack(PKArgs a) {
  __shared__ __align__(16) u16 lds[8][1032];
  int b = blockIdx.x;
  int r = 0;
  while (b >= a.cum[r + 1]) ++r;
  cvt_body(a.src[r], a.dst[r], b - a.cum[r], a.nspan[r], a.klog[r], lds);
}

// ---------- pipelined dual-mtile K-segment: 4-kstep groups, double-buffered ----
// PLAIN cached loads. Safe: every A (h-state) buffer is per-timestep private,
// written once via coherent (L2-bypass) store BEFORE its first cached read.
__device__ __forceinline__ void seg_mm(
    const short8* __restrict__ ap, const short8* __restrict__ wp, int ks,
    int sb, int se, f32x4& acc0, f32x4& acc1)
{
  if (sb >= se) return;
  short8 xa0[4], xb0[4], wv0[4], xa1[4], xb1[4], wv1[4];
#define LDG(B, S) { _Pragma("unroll") for (int d = 0; d < 4; ++d) { \
    xa##B[d] = ap[(long)((S) + d) * 64]; \
    xb##B[d] = ap[(long)(ks + (S) + d) * 64]; \
    wv##B[d] = wp[(long)((S) + d) * 64]; } }
#define MMG(B) { _Pragma("unroll") for (int d = 0; d < 4; ++d) { \
    acc0 = __builtin_amdgcn_mfma_f32_16x16x32_bf16(xa##B[d], wv##B[d], acc0, 0, 0, 0); \
    acc1 = __builtin_amdgcn_mfma_f32_16x16x32_bf16(xb##B[d], wv##B[d], acc1, 0, 0, 0); } }
  int s = sb;
  const int ng = (se - sb) >> 2;
  LDG(0, s)
  for (int g = 0; g < ng; g += 2) {
    LDG(1, s + 4)
    __builtin_amdgcn_sched_barrier(0);
    MMG(0)
    if (g + 2 < ng) LDG(0, s + 8)
    __builtin_amdgcn_sched_barrier(0);
    MMG(1)
    s += 8;
  }
#undef LDG
#undef MMG
}

// ---------- xpre = X (SBxK packed) @ W (NxK packed)^T, fp32 out ----------
__global__ __launch_bounds__(256) void gemm_pre(
    const u16* __restrict__ A, const u16* __restrict__ W,
    float* __restrict__ C, int N, int K)
{
  const int ks = K >> 5;
  const int m0 = blockIdx.x * 64;
  const int n0 = blockIdx.y * 64;
  const int w = threadIdx.x >> 6;
  const int lane = threadIdx.x & 63;
  const int colr = lane & 15;
  const int kgrp = lane >> 4;
  f32x4 acc[4] = {{0.f,0.f,0.f,0.f},{0.f,0.f,0.f,0.f},{0.f,0.f,0.f,0.f},{0.f,0.f,0.f,0.f}};
  const short8* ap = (const short8*)A + (long)(m0 / 16 + w) * ks * 64 + lane;
  const short8* wp = (const short8*)W + (long)(n0 / 16) * ks * 64 + lane;
  short8 av0[2], bv0[8], av1[2], bv1[8];
#define LDP(B, S) { _Pragma("unroll") for (int d = 0; d < 2; ++d) { \
    av##B[d] = ap[(long)((S) + d) * 64]; \
    _Pragma("unroll") for (int ct = 0; ct < 4; ++ct) \
      bv##B[ct * 2 + d] = wp[((long)ct * ks + (S) + d) * 64]; } }
#define MMP(B) { _Pragma("unroll") for (int d = 0; d < 2; ++d) \
    _Pragma("unroll") for (int ct = 0; ct < 4; ++ct) \
      acc[ct] = __builtin_amdgcn_mfma_f32_16x16x32_bf16(av##B[d], bv##B[ct * 2 + d], acc[ct], 0, 0, 0); }
  LDP(0, 0)
  for (int s = 0; s < ks; s += 4) {
    LDP(1, s + 2)
    __builtin_amdgcn_sched_barrier(0);
    MMP(0)
    if (s + 4 < ks) LDP(0, s + 4)
    __builtin_amdgcn_sched_barrier(0);
    MMP(1)
  }
#undef LDP
#undef MMP
#pragma unroll
  for (int ct = 0; ct < 4; ++ct)
#pragma unroll
    for (int j = 0; j < 4; ++j)
      C[(long)(m0 + w * 16 + kgrp * 4 + j) * N + n0 + ct * 16 + colr] = acc[ct][j];
}

// ---------- persistent fused LSTM sequence kernel ----------
struct Cell {
  const u16 *A1, *W1, *A2, *W2;
  const float *pre, *bias;
  float *cbuf; u16 *hout; float *sigout;
  float *part; int *cnt;
  int K1, K2, dh, chunk, nslog, blkend;
};

struct SeqParams {
  const u16* wb[11];
  const float* bias6[6];
  u16 *eh0, *eh1, *eh2;     // per-timestep private h: base + t*32*H (u16)
  u16 *dh0, *dh1;
  u16 *dh2;                 // stride 32*D
  float* ec[3];
  float* dc3[3];
  const float* xpre;
  float* part; int* cnt;
  float* outp;
  int S, FUT, H, D, stage0, nstage, ride_per, rtot;
  const float* rsrc[5]; uint4* rdst[5];
  int rcum[6], rns[5], rklog[5];
  int* bar;   // tree: leaf i at bar[i*16] (i<32), root bar[512], phase bar[528]
};

// Flush-free grid barrier: monotonic relaxed agent atomics, 32-leaf tree.
// 512 blocks @ __launch_bounds__(256,2) = 2 blocks/CU co-resident on 256 CUs.
__device__ __forceinline__ void grid_sync(int* bar, int nblk, int& lphase) {
  __syncthreads();
  if (threadIdx.x == 0) {
    ++lphase;
    const int NL = 32;
    const int per = nblk / NL;
    const int leaf = (int)blockIdx.x & (NL - 1);
    int t = __hip_atomic_fetch_add(&bar[leaf * 16], 1, __ATOMIC_RELAXED, __HIP_MEMORY_SCOPE_AGENT);
    if (t == lphase * per - 1) {
      int r = __hip_atomic_fetch_add(&bar[NL * 16], 1, __ATOMIC_RELAXED, __HIP_MEMORY_SCOPE_AGENT);
      if (r == lphase * NL - 1)
        __hip_atomic_store(&bar[NL * 16 + 16], lphase, __ATOMIC_RELAXED, __HIP_MEMORY_SCOPE_AGENT);
    }
    while (__hip_atomic_load(&bar[NL * 16 + 16], __ATOMIC_RELAXED, __HIP_MEMORY_SCOPE_AGENT) < lphase)
      __builtin_amdgcn_s_sleep(2);
  }
  __syncthreads();
}

// Work decomposition (grid=512):
//   encoder stages: c1/c2/c3 nslog=0 -> 192 items, NO split-K atomics at all;
//   remaining blocks run ride conversions.
//   decoder stages: c1/c2 nslog=1 (128 each), cell3 nslog=0 (256 items,
//   no split-K) -> 512 items, one round.
__device__ int build_stage(const SeqParams& p, int st, Cell c[3]) {
  const int H = p.H, D = p.D;
  const long sH = (long)32 * H;
  const long sD = (long)32 * D;
  const long PARTSTRIDE = (long)256 * 8 * 4 * 512;
  int blk = 0, nc = 0;
  auto add = [&](const u16* A1, const u16* W1, int K1,
                 const u16* A2, const u16* W2, int K2,
                 const float* pre, const float* bs, float* cb, u16* ho,
                 float* so, int dh, int nslog, int pi) {
    Cell& cd = c[nc];
    cd.A1 = A1; cd.W1 = W1; cd.K1 = K1;
    cd.A2 = A2; cd.W2 = W2; cd.K2 = K2;
    cd.pre = pre; cd.bias = bs;
    cd.cbuf = cb; cd.hout = ho; cd.sigout = so;
    cd.part = p.part + (long)pi * PARTSTRIDE;
    cd.cnt = p.cnt + pi * 256;
    cd.dh = dh; cd.nslog = nslog;
    cd.chunk = (K1 + K2) >> nslog;
    blk += (dh / 16) << nslog;
    cd.blkend = blk;
    ++nc;
  };
  if (st < p.S + 2) {
    int d = st, t = d;
    if (t < p.S)
      add(p.eh0 + t * sH, p.wb[1], H, nullptr, nullptr, 0,
          p.xpre + (long)t * 32 * 4 * H, p.bias6[0],
          p.ec[0], p.eh0 + (t + 1) * sH, nullptr, H, 0, 0);
    t = d - 1;
    if (t >= 0 && t < p.S)
      add(p.eh0 + (t + 1) * sH, p.wb[2], H, p.eh1 + t * sH, p.wb[3], H,
          nullptr, p.bias6[1], p.ec[1], p.eh1 + (t + 1) * sH, nullptr,
          H, 0, 1);
    t = d - 2;
    if (t >= 0 && t < p.S)
      add(p.eh1 + (t + 1) * sH, p.wb[4], H, p.eh2 + t * sH, p.wb[5], H,
          nullptr, p.bias6[2], p.ec[2], p.eh2 + (t + 1) * sH, nullptr,
          H, 0, 2);
  } else {
    int d = st - (p.S + 2), t = d;
    if (t < p.FUT) {
      const u16* hprev = (t == 0) ? (p.eh2 + p.S * sH) : (p.dh0 + t * sH);
      add(hprev, p.wb[6], H, nullptr, nullptr, 0,
          nullptr, p.bias6[3], p.dc3[0], p.dh0 + (t + 1) * sH, nullptr,
          H, 1, 0);
    }
    t = d - 1;
    if (t >= 0 && t < p.FUT)
      add(p.dh0 + (t + 1) * sH, p.wb[7], H, p.dh1 + t * sH, p.wb[8], H,
          nullptr, p.bias6[4], p.dc3[1], p.dh1 + (t + 1) * sH, nullptr,
          H, 1, 1);
    t = d - 2;
    if (t >= 0 && t < p.FUT)
      add(p.dh1 + (t + 1) * sH, p.wb[9], H, p.dh2 + t * sD, p.wb[10], D,
          nullptr, p.bias6[5], p.dc3[2], p.dh2 + (t + 1) * sD,
          p.outp + (long)t * 32 * D, D, 0, 2);
  }
  return blk;
}

__device__ void lstm_item(const Cell& cd, int local, void* smemraw, int* swinp) {
  const int nslog = cd.nslog;
  const int nsplit = 1 << nslog;
  const int tile = local >> nslog;
  const int split = local & (nsplit - 1);
  const int g = threadIdx.x >> 6;
  const int lane = threadIdx.x & 63;
  const int colr = lane & 15;
  const int kgrp = lane >> 4;
  const int dh = cd.dh;
  const int dh16 = dh >> 4;
  const int K1 = cd.K1, K2 = cd.K2;

  f32x4 acc0 = {0.f, 0.f, 0.f, 0.f};
  f32x4 acc1 = {0.f, 0.f, 0.f, 0.f};
  const int kbeg = split * cd.chunk;
  const int kend = kbeg + cd.chunk;

  if (kbeg < K1) {
    const int e = kend < K1 ? kend : K1;
    const int ks = K1 >> 5;
    seg_mm((const short8*)cd.A1 + lane,
           (const short8*)cd.W1 + (long)(g * dh16 + tile) * ks * 64 + lane,
           ks, kbeg >> 5, e >> 5, acc0, acc1);
  }
  if (kend > K1 && K2 > 0) {
    const int b0 = kbeg > K1 ? kbeg : K1;
    const int ks = K2 >> 5;
    seg_mm((const short8*)cd.A2 + lane,
           (const short8*)cd.W2 + (long)(g * dh16 + tile) * ks * 64 + lane,
           ks, (b0 - K1) >> 5, (kend - K1) >> 5, acc0, acc1);
  }

  if (nsplit > 1) {
    // split-K partials, plane-major [j][lane]: dense 512B per instruction.
    u64* base = (u64*)(cd.part + ((long)((tile << nslog) + split) * 4 + g) * 512);
    st64coh(base + 0 * 64 + lane, packf2(acc0[0], acc0[1]));
    st64coh(base + 1 * 64 + lane, packf2(acc0[2], acc0[3]));
    st64coh(base + 2 * 64 + lane, packf2(acc1[0], acc1[1]));
    st64coh(base + 3 * 64 + lane, packf2(acc1[2], acc1[3]));
    __threadfence_block();
    __syncthreads();
    if (threadIdx.x == 0)
      *swinp = (atomicAdd(&cd.cnt[tile], 1) == nsplit - 1) ? 1 : 0;
    __syncthreads();
    if (!*swinp) return;
    __threadfence_block();
    for (int os = 0; os < nsplit; ++os) {
      if (os == split) continue;
      const u64* obase = (const u64*)(cd.part + ((long)((tile << nslog) + os) * 4 + g) * 512);
      u64 q0 = ld64coh(obase + 0 * 64 + lane);
      u64 q1 = ld64coh(obase + 1 * 64 + lane);
      u64 q2 = ld64coh(obase + 2 * 64 + lane);
      u64 q3 = ld64coh(obase + 3 * 64 + lane);
      union { u64 u; float f[2]; } t;
      t.u = q0; acc0[0] += t.f[0]; acc0[1] += t.f[1];
      t.u = q1; acc0[2] += t.f[0]; acc0[3] += t.f[1];
      t.u = q2; acc1[0] += t.f[0]; acc1[1] += t.f[1];
      t.u = q3; acc1[2] += t.f[0]; acc1[3] += t.f[1];
    }
    if (threadIdx.x == 0)
      __hip_atomic_store(&cd.cnt[tile], 0, __ATOMIC_RELAXED, __HIP_MEMORY_SCOPE_AGENT);
  }

  float (*ldsG)[16][33] = (float (*)[16][33])smemraw;
#pragma unroll
  for (int j = 0; j < 4; ++j) {
    ldsG[g][colr][kgrp * 4 + j] = acc0[j];
    ldsG[g][colr][16 + kgrp * 4 + j] = acc1[j];
  }
  __syncthreads();

  if (threadIdx.x < 64) {
    const int b2 = threadIdx.x >> 1;
    const int half = threadIdx.x & 1;
    const int u0l = half * 8;
    const int u0 = tile * 16 + u0l;
    // c-state address is reused every stage -> coherent path (small)
    const u64* crd = (const u64*)(cd.cbuf + (long)b2 * dh + u0);
    u64 cw[4];
#pragma unroll
    for (int q = 0; q < 4; ++q) cw[q] = ld64coh(crd + q);
    float hv[8], cv[8], sv[8];
#pragma unroll
    for (int e = 0; e < 8; ++e) {
      int ul = u0l + e;
      int u = tile * 16 + ul;
      float gi = ldsG[0][ul][b2] + cd.bias[u];
      float gf = ldsG[1][ul][b2] + cd.bias[dh + u];
      float gg = ldsG[2][ul][b2] + cd.bias[2 * dh + u];
      float go = ldsG[3][ul][b2] + cd.bias[3 * dh + u];
      if (cd.pre) {
        const float* pb = cd.pre + (long)b2 * 4 * dh;
        gi += pb[u]; gf += pb[dh + u]; gg += pb[2 * dh + u]; go += pb[3 * dh + u];
      }
      union { u64 q; float f[2]; } cu; cu.q = cw[e >> 1];
      float cold = cu.f[e & 1];
      float cn = sigm(gf) * cold + sigm(gi) * tanh_fast(gg);
      cv[e] = cn;
      float h = sigm(go) * tanh_fast(cn);
      hv[e] = h;
      sv[e] = sigm(h);
    }
    u64* cwr = (u64*)(cd.cbuf + (long)b2 * dh + u0);
#pragma unroll
    for (int q = 0; q < 4; ++q)
      st64coh(cwr + q, packf2(cv[2 * q], cv[2 * q + 1]));
    const int ksh = dh >> 5;
    const int mt = b2 >> 4;
    const int kstep = u0 >> 5;
    const int lanep = (b2 & 15) + 16 * ((u0 >> 3) & 3);
    uint4 hp;
    hp.x = pack2bf(hv[0], hv[1]); hp.y = pack2bf(hv[2], hv[3]);
    hp.z = pack2bf(hv[4], hv[5]); hp.w = pack2bf(hv[6], hv[7]);
    // h published via coherent store (L2-bypass); next stage reads it CACHED
    u64* hq = (u64*)&((uint4*)cd.hout)[((long)mt * ksh + kstep) * 64 + lanep];
    st64coh(hq,     (u64)hp.x | ((u64)hp.y << 32));
    st64coh(hq + 1, (u64)hp.z | ((u64)hp.w << 32));
    if (cd.sigout) {
      float4* sp = (float4*)(cd.sigout + (long)b2 * dh + u0);
      sp[0] = make_float4(sv[0], sv[1], sv[2], sv[3]);
      sp[1] = make_float4(sv[4], sv[5], sv[6], sv[7]);
    }
  }
}

__global__ __launch_bounds__(256, 2) void lstm_seq(SeqParams p) {
  __shared__ __align__(16) char smem[16512];   // union: cvt lds (16512B) / ldsG (8448B)
  __shared__ int swin;
  int lphase = 0;

  for (int sti = 0; sti < p.nstage; ++sti) {
    const int st = p.stage0 + sti;
    Cell cells[3];
    const int nl = build_stage(p, st, cells);
    int rs = 0, rc = 0;
    if (st < p.S + 2) {
      rs = st * p.ride_per;
      rc = p.rtot - rs;
      if (rc < 0) rc = 0;
      if (rc > p.ride_per) rc = p.ride_per;
    }
    const int total = nl + rc;
    for (int it = blockIdx.x; it < total; it += (int)gridDim.x) {
      __syncthreads();                 // LDS reuse guard between items
      if (it < nl) {
        int ci = 0, bstart = 0;
        while (it >= cells[ci].blkend) { bstart = cells[ci].blkend; ++ci; }
        lstm_item(cells[ci], it - bstart, (void*)smem, &swin);
      } else {
        int pb = it - nl + rs;
        int r = 0;
        while (pb >= p.rcum[r + 1]) ++r;
        cvt_body(p.rsrc[r], p.rdst[r], pb - p.rcum[r], p.rns[r], p.rklog[r],
                 (u16 (*)[1032])smem);
      }
    }
    if (sti + 1 < p.nstage) grid_sync(p.bar, (int)gridDim.x, lphase);
  }
}

// ------------------------------- host -----------------------------------------
extern "C" void kernel_launch(void* const* d_in, const int* in_sizes, int n_in,
                              void* d_out, int out_size, void* d_ws, size_t ws_size,
                              hipStream_t stream)
{
  const float* x_f = (const float*)d_in[0];
  const float* Wih[6]; const float* Whh[6]; const float* bias[6];
  for (int c = 0; c < 6; ++c) {
    Wih[c]  = (const float*)d_in[2 + 3 * c];
    Whh[c]  = (const float*)d_in[3 + 3 * c];
    bias[c] = (const float*)d_in[4 + 3 * c];
  }
  const int H = in_sizes[4] / 4;          // 1024
  const int D = in_sizes[2] / (4 * H);    // 4096
  const int B = 32;
  const int SB = in_sizes[0] / D;         // 640
  const int S = SB / B;                   // 20
  const int FUT = out_size / (B * D);     // 10
  (void)n_in; (void)ws_size;
  int klogH = 31 - __builtin_clz((unsigned)H);
  int klogD = 31 - __builtin_clz((unsigned)D);

  char* wsp = (char*)d_ws;
  size_t off = 0;
  auto alloc = [&](size_t bytes) -> void* {
    off = (off + 255) & ~(size_t)255;
    void* p = (void*)(wsp + off);
    off += bytes;
    return p;
  };

  const float* wsrc[11] = { Wih[0], Whh[0], Wih[1], Whh[1], Wih[2], Whh[2],
                            Whh[3], Wih[4], Whh[4], Wih[5], Whh[5] };
  long welems[11] = { (long)4*H*D, (long)4*H*H, (long)4*H*H, (long)4*H*H,
                      (long)4*H*H, (long)4*H*H, (long)4*H*H, (long)4*H*H,
                      (long)4*H*H, (long)4*D*H, (long)4*D*(long)D };
  int wrows[11] = { 4*H, 4*H, 4*H, 4*H, 4*H, 4*H, 4*H, 4*H, 4*H, 4*D, 4*D };
  int wklog[11] = { klogD, klogH, klogH, klogH, klogH, klogH,
                    klogH, klogH, klogH, klogH, klogD };
  u16* wb[11];
  for (int i = 0; i < 11; ++i) wb[i] = (u16*)alloc((size_t)welems[i] * 2);
  u16* xbf = (u16*)alloc((size_t)SB * D * 2);
  float* xpre = (float*)alloc((size_t)SB * D * 4);

  size_t zbeg = (off + 255) & ~(size_t)255;
  int* cnt = (int*)alloc(3 * 256 * 4);
  int* gbar = (int*)alloc(16384);         // two independent barrier trees
  const long sH = (long)B * H;            // u16 elems per h slot
  const long sD = (long)B * D;
  u16* eh0 = (u16*)alloc((size_t)(S + 1) * sH * 2);
  u16* eh1 = (u16*)alloc((size_t)(S + 1) * sH * 2);
  u16* eh2 = (u16*)alloc((size_t)(S + 1) * sH * 2);
  u16* dh0 = (u16*)alloc((size_t)(FUT + 1) * sH * 2);
  u16* dh1 = (u16*)alloc((size_t)(FUT + 1) * sH * 2);
  u16* dh2 = (u16*)alloc((size_t)(FUT + 1) * sD * 2);
  float* ec[3]; float* dc[3];
  for (int c = 0; c < 3; ++c) ec[c] = (float*)alloc((size_t)B * H * 4);
  dc[0] = (float*)alloc((size_t)B * H * 4);
  dc[1] = (float*)alloc((size_t)B * H * 4);
  dc[2] = (float*)alloc((size_t)B * D * 4);
  size_t zend = off;

  const long PARTSTRIDE = (long)256 * 8 * 4 * 512;   // floats per cell slot region
  float* part = (float*)alloc((size_t)3 * PARTSTRIDE * 4);

  hipMemsetAsync((void*)(wsp + zbeg), 0, zend - zbeg, stream);

  // ---- upfront conversion: encoder weights (wsrc[0..5]) + x ----
  PKArgs pa;
  int cum = 0;
  for (int i = 0; i < 7; ++i) {
    int rows, klog;
    if (i < 6) { rows = wrows[i]; klog = wklog[i]; pa.src[i] = wsrc[i]; pa.dst[i] = (uint4*)wb[i]; }
    else       { rows = SB;       klog = klogD;    pa.src[i] = x_f;     pa.dst[i] = (uint4*)xbf; }
    int ns = 1 << (klog - 10);
    pa.cum[i] = cum;
    pa.nspan[i] = ns;
    pa.klog[i] = klog;
    cum += (rows / 8) * ns;
  }
  for (int i = 7; i <= NPK; ++i) pa.cum[i] = cum;
  cvt_pack<<<dim3(cum), dim3(256), 0, stream>>>(pa);

  gemm_pre<<<dim3(SB / 64, (4 * H) / 64), dim3(256), 0, stream>>>(xbf, wb[0], xpre, 4 * H, D);

  // ---- persistent sequence kernels: encoder (+rides), then decoder ----
  SeqParams sp;
  for (int i = 0; i < 11; ++i) sp.wb[i] = wb[i];
  for (int i = 0; i < 6; ++i) sp.bias6[i] = bias[i];
  sp.eh0 = eh0; sp.eh1 = eh1; sp.eh2 = eh2;
  sp.dh0 = dh0; sp.dh1 = dh1; sp.dh2 = dh2;
  for (int c = 0; c < 3; ++c) { sp.ec[c] = ec[c]; sp.dc3[c] = dc[c]; }
  sp.xpre = xpre; sp.part = part; sp.cnt = cnt;
  sp.outp = (float*)d_out;
  sp.S = S; sp.FUT = FUT; sp.H = H; sp.D = D;
  int rcum = 0;
  for (int i = 0; i < 5; ++i) {
    int wi = 6 + i;
    sp.rsrc[i] = wsrc[wi];
    sp.rdst[i] = (uint4*)wb[wi];
    int ns = 1 << (wklog[wi] - 10);
    sp.rcum[i] = rcum;
    sp.rns[i] = ns;
    sp.rklog[i] = wklog[wi];
    rcum += (wrows[wi] / 8) * ns;
  }
  sp.rcum[5] = rcum;
  sp.rtot = rcum;
  sp.ride_per = (rcum + (S + 2) - 1) / (S + 2);

  // encoder dispatch: stages [0, S+2), rides included
  sp.stage0 = 0;
  sp.nstage = S + 2;
  sp.bar = gbar;
  lstm_seq<<<dim3(512), dim3(256), 0, stream>>>(sp);

  // decoder dispatch: stages [S+2, S+2+FUT+2). Kernel boundary publishes the
  // ride-converted decoder weights (plain stores) to all XCDs.
  sp.stage0 = S + 2;
  sp.nstage = FUT + 2;
  sp.bar = gbar + 2048;
  lstm_seq<<<dim3(512), dim3(256), 0, stream>>>(sp);
}

// Round 10
// 1153.616 us; speedup vs baseline: 1.1669x; 1.0486x over previous
//
#include <hip/hip_runtime.h>

typedef __attribute__((ext_vector_type(8))) short short8;
typedef __attribute__((ext_vector_type(4))) float f32x4;
typedef unsigned short u16;
typedef unsigned long long u64;

__device__ __forceinline__ unsigned short f2bf(float f) {
  union { float f; unsigned u; } v; v.f = f;
  unsigned r = v.u + 0x7fffu + ((v.u >> 16) & 1u);
  return (unsigned short)(r >> 16);
}
__device__ __forceinline__ unsigned pack2bf(float lo, float hi) {
  return (unsigned)f2bf(lo) | ((unsigned)f2bf(hi) << 16);
}
__device__ __forceinline__ float sigm(float x) { return 1.0f / (1.0f + __expf(-x)); }
__device__ __forceinline__ float tanh_fast(float x) { return 1.0f - 2.0f / (__expf(2.0f * x) + 1.0f); }

// relaxed agent-scope (coherent-point) helpers: bypass L1/L2, NO cache flush.
__device__ __forceinline__ void st64coh(u64* p, u64 v) {
  __hip_atomic_store(p, v, __ATOMIC_RELAXED, __HIP_MEMORY_SCOPE_AGENT);
}
__device__ __forceinline__ u64 ld64coh(const u64* p) {
  return __hip_atomic_load(p, __ATOMIC_RELAXED, __HIP_MEMORY_SCOPE_AGENT);
}
__device__ __forceinline__ u64 packf2(float a, float b) {
  union { float f[2]; u64 u; } t; t.f[0] = a; t.f[1] = b; return t.u;
}

// ---------- fp32 -> bf16 convert + pack into MFMA-fragment order ----------
// packed blob: [tile16][kstep32][lane64][8]; lane = (row&15) + 16*((k>>3)&3).
// Plain stores (dense 16B). Rides run on DEDICATED blocks in the encoder
// dispatch; the encoder->decoder kernel boundary publishes them to all XCDs.
__device__ __forceinline__ void cvt_body(const float* __restrict__ src,
                                         uint4* __restrict__ dst,
                                         int lb, int ns, int klog,
                                         u16 (*lds)[1032]) {
  int ht = lb / ns, span = lb - ht * ns;
  long row0 = (long)ht * 8;
  int c0 = span << 10;

  const int tr = threadIdx.x >> 5, tc = threadIdx.x & 31;
  const float* srow = src + ((row0 + tr) << klog) + c0;
#pragma unroll
  for (int p = 0; p < 8; ++p) {
    int col = p * 128 + tc * 4;
    float4 v = *(const float4*)(srow + col);
    *(uint2*)&lds[tr][col] = make_uint2(pack2bf(v.x, v.y), pack2bf(v.z, v.w));
  }
  __syncthreads();
  int tile = ht >> 1, h0 = (ht & 1) * 8;
  long ks = 1l << (klog - 5);
  uint4* dbase = dst + ((long)tile * ks + span * 32) * 64 + h0;
#pragma unroll
  for (int i = 0; i < 4; ++i) {
    int ci = threadIdx.x + 256 * i;
    int rr = ci & 7, kgrp = (ci >> 3) & 3, kstep = ci >> 5;
    dbase[(long)kstep * 64 + rr + 16 * kgrp] = *(const uint4*)&lds[rr][kstep * 32 + kgrp * 8];
  }
}

#define NPK 12
struct PKArgs {
  const float* src[NPK];
  uint4* dst[NPK];
  int cum[NPK + 1];
  int nspan[NPK];
  int klog[NPK];
};

__global__ __launch_bounds__(256) void cvt_pack(PKArgs a) {
  __shared__ __align__(16) u16 lds[8][1032];
  int b = blockIdx.x;
  int r = 0;
  while (b >= a.cum[r + 1]) ++r;
  cvt_body(a.src[r], a.dst[r], b - a.cum[r], a.nspan[r], a.klog[r], lds);
}

// ---------- pipelined dual-mtile K-segment: 4-kstep groups, double-buffered ----
// PLAIN cached loads. Safe: every A (h-state) buffer is per-timestep private,
// written once via coherent (L2-bypass) store BEFORE its first cached read.
__device__ __forceinline__ void seg_mm(
    const short8* __restrict__ ap, const short8* __restrict__ wp, int ks,
    int sb, int se, f32x4& acc0, f32x4& acc1)
{
  if (sb >= se) return;
  short8 xa0[4], xb0[4], wv0[4], xa1[4], xb1[4], wv1[4];
#define LDG(B, S) { _Pragma("unroll") for (int d = 0; d < 4; ++d) { \
    xa##B[d] = ap[(long)((S) + d) * 64]; \
    xb##B[d] = ap[(long)(ks + (S) + d) * 64]; \
    wv##B[d] = wp[(long)((S) + d) * 64]; } }
#define MMG(B) { _Pragma("unroll") for (int d = 0; d < 4; ++d) { \
    acc0 = __builtin_amdgcn_mfma_f32_16x16x32_bf16(xa##B[d], wv##B[d], acc0, 0, 0, 0); \
    acc1 = __builtin_amdgcn_mfma_f32_16x16x32_bf16(xb##B[d], wv##B[d], acc1, 0, 0, 0); } }
  int s = sb;
  const int ng = (se - sb) >> 2;
  LDG(0, s)
  for (int g = 0; g < ng; g += 2) {
    LDG(1, s + 4)
    __builtin_amdgcn_sched_barrier(0);
    MMG(0)
    if (g + 2 < ng) LDG(0, s + 8)
    __builtin_amdgcn_sched_barrier(0);
    MMG(1)
    s += 8;
  }
#undef LDG
#undef MMG
}

// ---------- xpre = X (SBxK packed) @ W (NxK packed)^T, fp32 out ----------
__global__ __launch_bounds__(256) void gemm_pre(
    const u16* __restrict__ A, const u16* __restrict__ W,
    float* __restrict__ C, int N, int K)
{
  const int ks = K >> 5;
  const int m0 = blockIdx.x * 64;
  const int n0 = blockIdx.y * 64;
  const int w = threadIdx.x >> 6;
  const int lane = threadIdx.x & 63;
  const int colr = lane & 15;
  const int kgrp = lane >> 4;
  f32x4 acc[4] = {{0.f,0.f,0.f,0.f},{0.f,0.f,0.f,0.f},{0.f,0.f,0.f,0.f},{0.f,0.f,0.f,0.f}};
  const short8* ap = (const short8*)A + (long)(m0 / 16 + w) * ks * 64 + lane;
  const short8* wp = (const short8*)W + (long)(n0 / 16) * ks * 64 + lane;
  short8 av0[2], bv0[8], av1[2], bv1[8];
#define LDP(B, S) { _Pragma("unroll") for (int d = 0; d < 2; ++d) { \
    av##B[d] = ap[(long)((S) + d) * 64]; \
    _Pragma("unroll") for (int ct = 0; ct < 4; ++ct) \
      bv##B[ct * 2 + d] = wp[((long)ct * ks + (S) + d) * 64]; } }
#define MMP(B) { _Pragma("unroll") for (int d = 0; d < 2; ++d) \
    _Pragma("unroll") for (int ct = 0; ct < 4; ++ct) \
      acc[ct] = __builtin_amdgcn_mfma_f32_16x16x32_bf16(av##B[d], bv##B[ct * 2 + d], acc[ct], 0, 0, 0); }
  LDP(0, 0)
  for (int s = 0; s < ks; s += 4) {
    LDP(1, s + 2)
    __builtin_amdgcn_sched_barrier(0);
    MMP(0)
    if (s + 4 < ks) LDP(0, s + 4)
    __builtin_amdgcn_sched_barrier(0);
    MMP(1)
  }
#undef LDP
#undef MMP
#pragma unroll
  for (int ct = 0; ct < 4; ++ct)
#pragma unroll
    for (int j = 0; j < 4; ++j)
      C[(long)(m0 + w * 16 + kgrp * 4 + j) * N + n0 + ct * 16 + colr] = acc[ct][j];
}

// ---------- persistent fused LSTM sequence kernel ----------
struct Cell {
  const u16 *A1, *W1, *A2, *W2;
  const float *pre, *bias;
  float *cbuf; u16 *hout; float *sigout;
  float *part; int *cnt;
  int K1, K2, dh, chunk, nslog, blkend;
};

struct SeqParams {
  const u16* wb[11];
  const float* bias6[6];
  u16 *eh0, *eh1, *eh2;     // per-timestep private h: base + t*32*H (u16)
  u16 *dh0, *dh1;
  u16 *dh2;                 // stride 32*D
  float* ec[3];
  float* dc3[3];
  const float* xpre;
  float* part; int* cnt;
  float* outp;
  int S, FUT, H, D, stage0, nstage, nlstm, rtot;
  const float* rsrc[5]; uint4* rdst[5];
  int rcum[6], rns[5], rklog[5];
  int* bar;   // tree: leaf i at bar[i*16] (i<32), root bar[512], phase bar[528]
};

// Flush-free grid barrier over the first nblk blocks only (nblk % 32 == 0).
// All counted blocks are co-resident: grid 512 @ __launch_bounds__(256,2).
__device__ __forceinline__ void grid_sync(int* bar, int nblk, int& lphase) {
  __syncthreads();
  if (threadIdx.x == 0) {
    ++lphase;
    const int NL = 32;
    const int per = nblk / NL;
    const int leaf = (int)blockIdx.x & (NL - 1);
    int t = __hip_atomic_fetch_add(&bar[leaf * 16], 1, __ATOMIC_RELAXED, __HIP_MEMORY_SCOPE_AGENT);
    if (t == lphase * per - 1) {
      int r = __hip_atomic_fetch_add(&bar[NL * 16], 1, __ATOMIC_RELAXED, __HIP_MEMORY_SCOPE_AGENT);
      if (r == lphase * NL - 1)
        __hip_atomic_store(&bar[NL * 16 + 16], lphase, __ATOMIC_RELAXED, __HIP_MEMORY_SCOPE_AGENT);
    }
    while (__hip_atomic_load(&bar[NL * 16 + 16], __ATOMIC_RELAXED, __HIP_MEMORY_SCOPE_AGENT) < lphase)
      __builtin_amdgcn_s_sleep(2);
  }
  __syncthreads();
}

// Work decomposition:
//   encoder dispatch (nlstm=256): c1/c2/c3 nslog=0 -> 192 items, one round,
//   NO split-K atomics; blocks 256..511 are DEDICATED ride blocks (no
//   barriers) streaming the decoder-weight conversion.
//   decoder dispatch (nlstm=512): c1/c2 nslog=1 (128 each), cell3 nslog=0
//   (256 items) -> 512 items, one round, no rides.
__device__ int build_stage(const SeqParams& p, int st, Cell c[3]) {
  const int H = p.H, D = p.D;
  const long sH = (long)32 * H;
  const long sD = (long)32 * D;
  const long PARTSTRIDE = (long)256 * 8 * 4 * 512;
  int blk = 0, nc = 0;
  auto add = [&](const u16* A1, const u16* W1, int K1,
                 const u16* A2, const u16* W2, int K2,
                 const float* pre, const float* bs, float* cb, u16* ho,
                 float* so, int dh, int nslog, int pi) {
    Cell& cd = c[nc];
    cd.A1 = A1; cd.W1 = W1; cd.K1 = K1;
    cd.A2 = A2; cd.W2 = W2; cd.K2 = K2;
    cd.pre = pre; cd.bias = bs;
    cd.cbuf = cb; cd.hout = ho; cd.sigout = so;
    cd.part = p.part + (long)pi * PARTSTRIDE;
    cd.cnt = p.cnt + pi * 256;
    cd.dh = dh; cd.nslog = nslog;
    cd.chunk = (K1 + K2) >> nslog;
    blk += (dh / 16) << nslog;
    cd.blkend = blk;
    ++nc;
  };
  if (st < p.S + 2) {
    int d = st, t = d;
    if (t < p.S)
      add(p.eh0 + t * sH, p.wb[1], H, nullptr, nullptr, 0,
          p.xpre + (long)t * 32 * 4 * H, p.bias6[0],
          p.ec[0], p.eh0 + (t + 1) * sH, nullptr, H, 0, 0);
    t = d - 1;
    if (t >= 0 && t < p.S)
      add(p.eh0 + (t + 1) * sH, p.wb[2], H, p.eh1 + t * sH, p.wb[3], H,
          nullptr, p.bias6[1], p.ec[1], p.eh1 + (t + 1) * sH, nullptr,
          H, 0, 1);
    t = d - 2;
    if (t >= 0 && t < p.S)
      add(p.eh1 + (t + 1) * sH, p.wb[4], H, p.eh2 + t * sH, p.wb[5], H,
          nullptr, p.bias6[2], p.ec[2], p.eh2 + (t + 1) * sH, nullptr,
          H, 0, 2);
  } else {
    int d = st - (p.S + 2), t = d;
    if (t < p.FUT) {
      const u16* hprev = (t == 0) ? (p.eh2 + p.S * sH) : (p.dh0 + t * sH);
      add(hprev, p.wb[6], H, nullptr, nullptr, 0,
          nullptr, p.bias6[3], p.dc3[0], p.dh0 + (t + 1) * sH, nullptr,
          H, 1, 0);
    }
    t = d - 1;
    if (t >= 0 && t < p.FUT)
      add(p.dh0 + (t + 1) * sH, p.wb[7], H, p.dh1 + t * sH, p.wb[8], H,
          nullptr, p.bias6[4], p.dc3[1], p.dh1 + (t + 1) * sH, nullptr,
          H, 1, 1);
    t = d - 2;
    if (t >= 0 && t < p.FUT)
      add(p.dh1 + (t + 1) * sH, p.wb[9], H, p.dh2 + t * sD, p.wb[10], D,
          nullptr, p.bias6[5], p.dc3[2], p.dh2 + (t + 1) * sD,
          p.outp + (long)t * 32 * D, D, 0, 2);
  }
  return blk;
}

__device__ void lstm_item(const Cell& cd, int local, void* smemraw, int* swinp) {
  const int nslog = cd.nslog;
  const int nsplit = 1 << nslog;
  const int tile = local >> nslog;
  const int split = local & (nsplit - 1);
  const int g = threadIdx.x >> 6;
  const int lane = threadIdx.x & 63;
  const int colr = lane & 15;
  const int kgrp = lane >> 4;
  const int dh = cd.dh;
  const int dh16 = dh >> 4;
  const int K1 = cd.K1, K2 = cd.K2;

  f32x4 acc0 = {0.f, 0.f, 0.f, 0.f};
  f32x4 acc1 = {0.f, 0.f, 0.f, 0.f};
  const int kbeg = split * cd.chunk;
  const int kend = kbeg + cd.chunk;

  if (kbeg < K1) {
    const int e = kend < K1 ? kend : K1;
    const int ks = K1 >> 5;
    seg_mm((const short8*)cd.A1 + lane,
           (const short8*)cd.W1 + (long)(g * dh16 + tile) * ks * 64 + lane,
           ks, kbeg >> 5, e >> 5, acc0, acc1);
  }
  if (kend > K1 && K2 > 0) {
    const int b0 = kbeg > K1 ? kbeg : K1;
    const int ks = K2 >> 5;
    seg_mm((const short8*)cd.A2 + lane,
           (const short8*)cd.W2 + (long)(g * dh16 + tile) * ks * 64 + lane,
           ks, (b0 - K1) >> 5, (kend - K1) >> 5, acc0, acc1);
  }

  if (nsplit > 1) {
    // split-K partials, plane-major [j][lane]: dense 512B per instruction.
    u64* base = (u64*)(cd.part + ((long)((tile << nslog) + split) * 4 + g) * 512);
    st64coh(base + 0 * 64 + lane, packf2(acc0[0], acc0[1]));
    st64coh(base + 1 * 64 + lane, packf2(acc0[2], acc0[3]));
    st64coh(base + 2 * 64 + lane, packf2(acc1[0], acc1[1]));
    st64coh(base + 3 * 64 + lane, packf2(acc1[2], acc1[3]));
    __threadfence_block();
    __syncthreads();
    if (threadIdx.x == 0)
      *swinp = (atomicAdd(&cd.cnt[tile], 1) == nsplit - 1) ? 1 : 0;
    __syncthreads();
    if (!*swinp) return;
    __threadfence_block();
    for (int os = 0; os < nsplit; ++os) {
      if (os == split) continue;
      const u64* obase = (const u64*)(cd.part + ((long)((tile << nslog) + os) * 4 + g) * 512);
      u64 q0 = ld64coh(obase + 0 * 64 + lane);
      u64 q1 = ld64coh(obase + 1 * 64 + lane);
      u64 q2 = ld64coh(obase + 2 * 64 + lane);
      u64 q3 = ld64coh(obase + 3 * 64 + lane);
      union { u64 u; float f[2]; } t;
      t.u = q0; acc0[0] += t.f[0]; acc0[1] += t.f[1];
      t.u = q1; acc0[2] += t.f[0]; acc0[3] += t.f[1];
      t.u = q2; acc1[0] += t.f[0]; acc1[1] += t.f[1];
      t.u = q3; acc1[2] += t.f[0]; acc1[3] += t.f[1];
    }
    if (threadIdx.x == 0)
      __hip_atomic_store(&cd.cnt[tile], 0, __ATOMIC_RELAXED, __HIP_MEMORY_SCOPE_AGENT);
  }

  float (*ldsG)[16][33] = (float (*)[16][33])smemraw;
#pragma unroll
  for (int j = 0; j < 4; ++j) {
    ldsG[g][colr][kgrp * 4 + j] = acc0[j];
    ldsG[g][colr][16 + kgrp * 4 + j] = acc1[j];
  }
  __syncthreads();

  if (threadIdx.x < 64) {
    const int b2 = threadIdx.x >> 1;
    const int half = threadIdx.x & 1;
    const int u0l = half * 8;
    const int u0 = tile * 16 + u0l;
    // c-state address is reused every stage -> coherent path (small)
    const u64* crd = (const u64*)(cd.cbuf + (long)b2 * dh + u0);
    u64 cw[4];
#pragma unroll
    for (int q = 0; q < 4; ++q) cw[q] = ld64coh(crd + q);
    float hv[8], cv[8], sv[8];
#pragma unroll
    for (int e = 0; e < 8; ++e) {
      int ul = u0l + e;
      int u = tile * 16 + ul;
      float gi = ldsG[0][ul][b2] + cd.bias[u];
      float gf = ldsG[1][ul][b2] + cd.bias[dh + u];
      float gg = ldsG[2][ul][b2] + cd.bias[2 * dh + u];
      float go = ldsG[3][ul][b2] + cd.bias[3 * dh + u];
      if (cd.pre) {
        const float* pb = cd.pre + (long)b2 * 4 * dh;
        gi += pb[u]; gf += pb[dh + u]; gg += pb[2 * dh + u]; go += pb[3 * dh + u];
      }
      union { u64 q; float f[2]; } cu; cu.q = cw[e >> 1];
      float cold = cu.f[e & 1];
      float cn = sigm(gf) * cold + sigm(gi) * tanh_fast(gg);
      cv[e] = cn;
      float h = sigm(go) * tanh_fast(cn);
      hv[e] = h;
      sv[e] = sigm(h);
    }
    u64* cwr = (u64*)(cd.cbuf + (long)b2 * dh + u0);
#pragma unroll
    for (int q = 0; q < 4; ++q)
      st64coh(cwr + q, packf2(cv[2 * q], cv[2 * q + 1]));
    const int ksh = dh >> 5;
    const int mt = b2 >> 4;
    const int kstep = u0 >> 5;
    const int lanep = (b2 & 15) + 16 * ((u0 >> 3) & 3);
    uint4 hp;
    hp.x = pack2bf(hv[0], hv[1]); hp.y = pack2bf(hv[2], hv[3]);
    hp.z = pack2bf(hv[4], hv[5]); hp.w = pack2bf(hv[6], hv[7]);
    // h published via coherent store (L2-bypass); next stage reads it CACHED
    u64* hq = (u64*)&((uint4*)cd.hout)[((long)mt * ksh + kstep) * 64 + lanep];
    st64coh(hq,     (u64)hp.x | ((u64)hp.y << 32));
    st64coh(hq + 1, (u64)hp.z | ((u64)hp.w << 32));
    if (cd.sigout) {
      float4* sp = (float4*)(cd.sigout + (long)b2 * dh + u0);
      sp[0] = make_float4(sv[0], sv[1], sv[2], sv[3]);
      sp[1] = make_float4(sv[4], sv[5], sv[6], sv[7]);
    }
  }
}

__global__ __launch_bounds__(256, 2) void lstm_seq(SeqParams p) {
  __shared__ __align__(16) char smem[16512];   // union: cvt lds (16512B) / ldsG (8448B)
  __shared__ int swin;

  if ((int)blockIdx.x >= p.nlstm) {
    // Dedicated ride blocks: stream ALL decoder-weight conversions with no
    // barrier participation; stream ordering (this dispatch finishes before
    // the decoder dispatch starts) guarantees availability.
    const int nr = (int)gridDim.x - p.nlstm;
    for (int pb = (int)blockIdx.x - p.nlstm; pb < p.rtot; pb += nr) {
      __syncthreads();                 // LDS reuse guard between items
      int r = 0;
      while (pb >= p.rcum[r + 1]) ++r;
      cvt_body(p.rsrc[r], p.rdst[r], pb - p.rcum[r], p.rns[r], p.rklog[r],
               (u16 (*)[1032])smem);
    }
    return;
  }

  int lphase = 0;
  for (int sti = 0; sti < p.nstage; ++sti) {
    const int st = p.stage0 + sti;
    Cell cells[3];
    const int nl = build_stage(p, st, cells);
    for (int it = blockIdx.x; it < nl; it += p.nlstm) {
      __syncthreads();                 // LDS reuse guard between items
      int ci = 0, bstart = 0;
      while (it >= cells[ci].blkend) { bstart = cells[ci].blkend; ++ci; }
      lstm_item(cells[ci], it - bstart, (void*)smem, &swin);
    }
    if (sti + 1 < p.nstage) grid_sync(p.bar, p.nlstm, lphase);
  }
}

// ------------------------------- host -----------------------------------------
extern "C" void kernel_launch(void* const* d_in, const int* in_sizes, int n_in,
                              void* d_out, int out_size, void* d_ws, size_t ws_size,
                              hipStream_t stream)
{
  const float* x_f = (const float*)d_in[0];
  const float* Wih[6]; const float* Whh[6]; const float* bias[6];
  for (int c = 0; c < 6; ++c) {
    Wih[c]  = (const float*)d_in[2 + 3 * c];
    Whh[c]  = (const float*)d_in[3 + 3 * c];
    bias[c] = (const float*)d_in[4 + 3 * c];
  }
  const int H = in_sizes[4] / 4;          // 1024
  const int D = in_sizes[2] / (4 * H);    // 4096
  const int B = 32;
  const int SB = in_sizes[0] / D;         // 640
  const int S = SB / B;                   // 20
  const int FUT = out_size / (B * D);     // 10
  (void)n_in; (void)ws_size;
  int klogH = 31 - __builtin_clz((unsigned)H);
  int klogD = 31 - __builtin_clz((unsigned)D);

  char* wsp = (char*)d_ws;
  size_t off = 0;
  auto alloc = [&](size_t bytes) -> void* {
    off = (off + 255) & ~(size_t)255;
    void* p = (void*)(wsp + off);
    off += bytes;
    return p;
  };

  const float* wsrc[11] = { Wih[0], Whh[0], Wih[1], Whh[1], Wih[2], Whh[2],
                            Whh[3], Wih[4], Whh[4], Wih[5], Whh[5] };
  long welems[11] = { (long)4*H*D, (long)4*H*H, (long)4*H*H, (long)4*H*H,
                      (long)4*H*H, (long)4*H*H, (long)4*H*H, (long)4*H*H,
                      (long)4*H*H, (long)4*D*H, (long)4*D*(long)D };
  int wrows[11] = { 4*H, 4*H, 4*H, 4*H, 4*H, 4*H, 4*H, 4*H, 4*H, 4*D, 4*D };
  int wklog[11] = { klogD, klogH, klogH, klogH, klogH, klogH,
                    klogH, klogH, klogH, klogH, klogD };
  u16* wb[11];
  for (int i = 0; i < 11; ++i) wb[i] = (u16*)alloc((size_t)welems[i] * 2);
  u16* xbf = (u16*)alloc((size_t)SB * D * 2);
  float* xpre = (float*)alloc((size_t)SB * D * 4);

  size_t zbeg = (off + 255) & ~(size_t)255;
  int* cnt = (int*)alloc(3 * 256 * 4);
  int* gbar = (int*)alloc(16384);         // two independent barrier trees
  const long sH = (long)B * H;            // u16 elems per h slot
  const long sD = (long)B * D;
  u16* eh0 = (u16*)alloc((size_t)(S + 1) * sH * 2);
  u16* eh1 = (u16*)alloc((size_t)(S + 1) * sH * 2);
  u16* eh2 = (u16*)alloc((size_t)(S + 1) * sH * 2);
  u16* dh0 = (u16*)alloc((size_t)(FUT + 1) * sH * 2);
  u16* dh1 = (u16*)alloc((size_t)(FUT + 1) * sH * 2);
  u16* dh2 = (u16*)alloc((size_t)(FUT + 1) * sD * 2);
  float* ec[3]; float* dc[3];
  for (int c = 0; c < 3; ++c) ec[c] = (float*)alloc((size_t)B * H * 4);
  dc[0] = (float*)alloc((size_t)B * H * 4);
  dc[1] = (float*)alloc((size_t)B * H * 4);
  dc[2] = (float*)alloc((size_t)B * D * 4);
  size_t zend = off;

  const long PARTSTRIDE = (long)256 * 8 * 4 * 512;   // floats per cell slot region
  float* part = (float*)alloc((size_t)3 * PARTSTRIDE * 4);

  hipMemsetAsync((void*)(wsp + zbeg), 0, zend - zbeg, stream);

  // ---- upfront conversion: encoder weights (wsrc[0..5]) + x ----
  PKArgs pa;
  int cum = 0;
  for (int i = 0; i < 7; ++i) {
    int rows, klog;
    if (i < 6) { rows = wrows[i]; klog = wklog[i]; pa.src[i] = wsrc[i]; pa.dst[i] = (uint4*)wb[i]; }
    else       { rows = SB;       klog = klogD;    pa.src[i] = x_f;     pa.dst[i] = (uint4*)xbf; }
    int ns = 1 << (klog - 10);
    pa.cum[i] = cum;
    pa.nspan[i] = ns;
    pa.klog[i] = klog;
    cum += (rows / 8) * ns;
  }
  for (int i = 7; i <= NPK; ++i) pa.cum[i] = cum;
  cvt_pack<<<dim3(cum), dim3(256), 0, stream>>>(pa);

  gemm_pre<<<dim3(SB / 64, (4 * H) / 64), dim3(256), 0, stream>>>(xbf, wb[0], xpre, 4 * H, D);

  // ---- persistent sequence kernels: encoder (+dedicated ride blocks), decoder ----
  SeqParams sp;
  for (int i = 0; i < 11; ++i) sp.wb[i] = wb[i];
  for (int i = 0; i < 6; ++i) sp.bias6[i] = bias[i];
  sp.eh0 = eh0; sp.eh1 = eh1; sp.eh2 = eh2;
  sp.dh0 = dh0; sp.dh1 = dh1; sp.dh2 = dh2;
  for (int c = 0; c < 3; ++c) { sp.ec[c] = ec[c]; sp.dc3[c] = dc[c]; }
  sp.xpre = xpre; sp.part = part; sp.cnt = cnt;
  sp.outp = (float*)d_out;
  sp.S = S; sp.FUT = FUT; sp.H = H; sp.D = D;
  int rcum = 0;
  for (int i = 0; i < 5; ++i) {
    int wi = 6 + i;
    sp.rsrc[i] = wsrc[wi];
    sp.rdst[i] = (uint4*)wb[wi];
    int ns = 1 << (wklog[wi] - 10);
    sp.rcum[i] = rcum;
    sp.rns[i] = ns;
    sp.rklog[i] = wklog[wi];
    rcum += (wrows[wi] / 8) * ns;
  }
  sp.rcum[5] = rcum;
  sp.rtot = rcum;

  // encoder dispatch: LSTM barrier group = blocks 0..255; ride blocks 256..511
  sp.stage0 = 0;
  sp.nstage = S + 2;
  sp.nlstm = 256;
  sp.bar = gbar;
  lstm_seq<<<dim3(512), dim3(256), 0, stream>>>(sp);

  // decoder dispatch: all 512 blocks in the barrier group, no rides.
  // Kernel boundary publishes ride-converted weights to all XCDs.
  sp.stage0 = S + 2;
  sp.nstage = FUT + 2;
  sp.nlstm = 512;
  sp.rtot = 0;
  sp.bar = gbar + 2048;
  lstm_seq<<<dim3(512), dim3(256), 0, stream>>>(sp);
}

// Round 11
// 1131.939 us; speedup vs baseline: 1.1893x; 1.0192x over previous
//
#include <hip/hip_runtime.h>

typedef __attribute__((ext_vector_type(8))) short short8;
typedef __attribute__((ext_vector_type(4))) float f32x4;
typedef unsigned short u16;
typedef unsigned long long u64;

__device__ __forceinline__ unsigned short f2bf(float f) {
  union { float f; unsigned u; } v; v.f = f;
  unsigned r = v.u + 0x7fffu + ((v.u >> 16) & 1u);
  return (unsigned short)(r >> 16);
}
__device__ __forceinline__ unsigned pack2bf(float lo, float hi) {
  return (unsigned)f2bf(lo) | ((unsigned)f2bf(hi) << 16);
}
__device__ __forceinline__ float sigm(float x) { return 1.0f / (1.0f + __expf(-x)); }
__device__ __forceinline__ float tanh_fast(float x) { return 1.0f - 2.0f / (__expf(2.0f * x) + 1.0f); }

// relaxed agent-scope (coherent-point) helpers: bypass L1/L2, NO cache flush.
__device__ __forceinline__ void st64coh(u64* p, u64 v) {
  __hip_atomic_store(p, v, __ATOMIC_RELAXED, __HIP_MEMORY_SCOPE_AGENT);
}
__device__ __forceinline__ u64 ld64coh(const u64* p) {
  return __hip_atomic_load(p, __ATOMIC_RELAXED, __HIP_MEMORY_SCOPE_AGENT);
}
__device__ __forceinline__ u64 packf2(float a, float b) {
  union { float f[2]; u64 u; } t; t.f[0] = a; t.f[1] = b; return t.u;
}

// ---------- fp32 -> bf16 convert + pack into MFMA-fragment order ----------
// packed blob: [tile16][kstep32][lane64][8]; lane = (row&15) + 16*((k>>3)&3).
// Plain stores (dense 16B). Rides run on DEDICATED blocks in the encoder
// dispatch; the encoder->decoder kernel boundary publishes them to all XCDs.
__device__ __forceinline__ void cvt_body(const float* __restrict__ src,
                                         uint4* __restrict__ dst,
                                         int lb, int ns, int klog,
                                         u16 (*lds)[1032]) {
  int ht = lb / ns, span = lb - ht * ns;
  long row0 = (long)ht * 8;
  int c0 = span << 10;

  const int tr = threadIdx.x >> 5, tc = threadIdx.x & 31;
  const float* srow = src + ((row0 + tr) << klog) + c0;
#pragma unroll
  for (int p = 0; p < 8; ++p) {
    int col = p * 128 + tc * 4;
    float4 v = *(const float4*)(srow + col);
    *(uint2*)&lds[tr][col] = make_uint2(pack2bf(v.x, v.y), pack2bf(v.z, v.w));
  }
  __syncthreads();
  int tile = ht >> 1, h0 = (ht & 1) * 8;
  long ks = 1l << (klog - 5);
  uint4* dbase = dst + ((long)tile * ks + span * 32) * 64 + h0;
#pragma unroll
  for (int i = 0; i < 4; ++i) {
    int ci = threadIdx.x + 256 * i;
    int rr = ci & 7, kgrp = (ci >> 3) & 3, kstep = ci >> 5;
    dbase[(long)kstep * 64 + rr + 16 * kgrp] = *(const uint4*)&lds[rr][kstep * 32 + kgrp * 8];
  }
}

#define NPK 12
struct PKArgs {
  const float* src[NPK];
  uint4* dst[NPK];
  int cum[NPK + 1];
  int nspan[NPK];
  int klog[NPK];
};

__global__ __launch_bounds__(256) void cvt_pack(PKArgs a) {
  __shared__ __align__(16) u16 lds[8][1032];
  int b = blockIdx.x;
  int r = 0;
  while (b >= a.cum[r + 1]) ++r;
  cvt_body(a.src[r], a.dst[r], b - a.cum[r], a.nspan[r], a.klog[r], lds);
}

// ---------- pipelined dual-mtile K-segment: 4-kstep groups, double-buffered ----
// PLAIN cached loads. Safe: every A (h-state) buffer is per-timestep private,
// written once via coherent (L2-bypass) store BEFORE its first cached read.
__device__ __forceinline__ void seg_mm(
    const short8* __restrict__ ap, const short8* __restrict__ wp, int ks,
    int sb, int se, f32x4& acc0, f32x4& acc1)
{
  if (sb >= se) return;
  short8 xa0[4], xb0[4], wv0[4], xa1[4], xb1[4], wv1[4];
#define LDG(B, S) { _Pragma("unroll") for (int d = 0; d < 4; ++d) { \
    xa##B[d] = ap[(long)((S) + d) * 64]; \
    xb##B[d] = ap[(long)(ks + (S) + d) * 64]; \
    wv##B[d] = wp[(long)((S) + d) * 64]; } }
#define MMG(B) { _Pragma("unroll") for (int d = 0; d < 4; ++d) { \
    acc0 = __builtin_amdgcn_mfma_f32_16x16x32_bf16(xa##B[d], wv##B[d], acc0, 0, 0, 0); \
    acc1 = __builtin_amdgcn_mfma_f32_16x16x32_bf16(xb##B[d], wv##B[d], acc1, 0, 0, 0); } }
  int s = sb;
  const int ng = (se - sb) >> 2;
  LDG(0, s)
  for (int g = 0; g < ng; g += 2) {
    LDG(1, s + 4)
    __builtin_amdgcn_sched_barrier(0);
    MMG(0)
    if (g + 2 < ng) LDG(0, s + 8)
    __builtin_amdgcn_sched_barrier(0);
    MMG(1)
    s += 8;
  }
#undef LDG
#undef MMG
}

// ---------- xpre = X (SBxK packed) @ W (NxK packed)^T, fp32 out ----------
__global__ __launch_bounds__(256) void gemm_pre(
    const u16* __restrict__ A, const u16* __restrict__ W,
    float* __restrict__ C, int N, int K)
{
  const int ks = K >> 5;
  const int m0 = blockIdx.x * 64;
  const int n0 = blockIdx.y * 64;
  const int w = threadIdx.x >> 6;
  const int lane = threadIdx.x & 63;
  const int colr = lane & 15;
  const int kgrp = lane >> 4;
  f32x4 acc[4] = {{0.f,0.f,0.f,0.f},{0.f,0.f,0.f,0.f},{0.f,0.f,0.f,0.f},{0.f,0.f,0.f,0.f}};
  const short8* ap = (const short8*)A + (long)(m0 / 16 + w) * ks * 64 + lane;
  const short8* wp = (const short8*)W + (long)(n0 / 16) * ks * 64 + lane;
  short8 av0[2], bv0[8], av1[2], bv1[8];
#define LDP(B, S) { _Pragma("unroll") for (int d = 0; d < 2; ++d) { \
    av##B[d] = ap[(long)((S) + d) * 64]; \
    _Pragma("unroll") for (int ct = 0; ct < 4; ++ct) \
      bv##B[ct * 2 + d] = wp[((long)ct * ks + (S) + d) * 64]; } }
#define MMP(B) { _Pragma("unroll") for (int d = 0; d < 2; ++d) \
    _Pragma("unroll") for (int ct = 0; ct < 4; ++ct) \
      acc[ct] = __builtin_amdgcn_mfma_f32_16x16x32_bf16(av##B[d], bv##B[ct * 2 + d], acc[ct], 0, 0, 0); }
  LDP(0, 0)
  for (int s = 0; s < ks; s += 4) {
    LDP(1, s + 2)
    __builtin_amdgcn_sched_barrier(0);
    MMP(0)
    if (s + 4 < ks) LDP(0, s + 4)
    __builtin_amdgcn_sched_barrier(0);
    MMP(1)
  }
#undef LDP
#undef MMP
#pragma unroll
  for (int ct = 0; ct < 4; ++ct)
#pragma unroll
    for (int j = 0; j < 4; ++j)
      C[(long)(m0 + w * 16 + kgrp * 4 + j) * N + n0 + ct * 16 + colr] = acc[ct][j];
}

// ---------- persistent fused LSTM sequence kernel ----------
struct Cell {
  const u16 *A1, *W1, *A2, *W2;
  const float *pre, *bias;
  float *cbuf; u16 *hout; float *sigout;
  float *part; int *cnt;
  int K1, K2, dh, chunk, nslog, blkend;
};

struct SeqParams {
  const u16* wb[11];
  const float* bias6[6];
  u16 *eh0, *eh1, *eh2;     // per-timestep private h: base + t*32*H (u16)
  u16 *dh0, *dh1;
  u16 *dh2;                 // stride 32*D
  float* ec[3];
  float* dc3[3];
  const float* xpre;
  float* part; int* cnt;
  float* outp;
  int S, FUT, H, D, stage0, nstage, nlstm, rtot;
  const float* rsrc[5]; uint4* rdst[5];
  int rcum[6], rns[5], rklog[5];
  int* bar;   // leaf cnt i: bar[i*16] (i<32); root cnt bar[512]; root phase
              // bar[528]; leaf phase i: bar[1024+i*16]
};

// Flush-free grid barrier, TWO-LEVEL RELEASE to kill poller serialization:
// only the 32 leaf-leaders (last arriver per leaf) poll the root phase word;
// each then publishes a leaf-local phase word polled by <=15 blocks.
// Max pollers per address: 32 (root) / 15 (leaf) vs 512 before.
// Arrival: monotonic relaxed agent fetch-adds (proven). nblk % 32 == 0.
__device__ __forceinline__ void grid_sync(int* bar, int nblk, int& lphase) {
  __syncthreads();
  if (threadIdx.x == 0) {
    ++lphase;
    const int NL = 32;
    const int per = nblk / NL;
    const int leaf = (int)blockIdx.x & (NL - 1);
    int t = __hip_atomic_fetch_add(&bar[leaf * 16], 1, __ATOMIC_RELAXED, __HIP_MEMORY_SCOPE_AGENT);
    if (t == lphase * per - 1) {
      // leaf leader: arrive at root, poll root phase, publish leaf phase
      int r = __hip_atomic_fetch_add(&bar[NL * 16], 1, __ATOMIC_RELAXED, __HIP_MEMORY_SCOPE_AGENT);
      if (r == lphase * NL - 1)
        __hip_atomic_store(&bar[NL * 16 + 16], lphase, __ATOMIC_RELAXED, __HIP_MEMORY_SCOPE_AGENT);
      while (__hip_atomic_load(&bar[NL * 16 + 16], __ATOMIC_RELAXED, __HIP_MEMORY_SCOPE_AGENT) < lphase)
        __builtin_amdgcn_s_sleep(2);
      __hip_atomic_store(&bar[1024 + leaf * 16], lphase, __ATOMIC_RELAXED, __HIP_MEMORY_SCOPE_AGENT);
    } else {
      while (__hip_atomic_load(&bar[1024 + leaf * 16], __ATOMIC_RELAXED, __HIP_MEMORY_SCOPE_AGENT) < lphase)
        __builtin_amdgcn_s_sleep(2);
    }
  }
  __syncthreads();
}

// Work decomposition:
//   encoder dispatch (nlstm=256): c1/c2/c3 nslog=0 -> 192 items, one round,
//   NO split-K atomics; blocks 256..511 are DEDICATED ride blocks (no
//   barriers) streaming the decoder-weight conversion.
//   decoder dispatch (nlstm=512): c1/c2 nslog=1 (128 each), cell3 nslog=0
//   (256 items) -> 512 items, one round, no rides.
__device__ int build_stage(const SeqParams& p, int st, Cell c[3]) {
  const int H = p.H, D = p.D;
  const long sH = (long)32 * H;
  const long sD = (long)32 * D;
  const long PARTSTRIDE = (long)256 * 8 * 4 * 512;
  int blk = 0, nc = 0;
  auto add = [&](const u16* A1, const u16* W1, int K1,
                 const u16* A2, const u16* W2, int K2,
                 const float* pre, const float* bs, float* cb, u16* ho,
                 float* so, int dh, int nslog, int pi) {
    Cell& cd = c[nc];
    cd.A1 = A1; cd.W1 = W1; cd.K1 = K1;
    cd.A2 = A2; cd.W2 = W2; cd.K2 = K2;
    cd.pre = pre; cd.bias = bs;
    cd.cbuf = cb; cd.hout = ho; cd.sigout = so;
    cd.part = p.part + (long)pi * PARTSTRIDE;
    cd.cnt = p.cnt + pi * 256;
    cd.dh = dh; cd.nslog = nslog;
    cd.chunk = (K1 + K2) >> nslog;
    blk += (dh / 16) << nslog;
    cd.blkend = blk;
    ++nc;
  };
  if (st < p.S + 2) {
    int d = st, t = d;
    if (t < p.S)
      add(p.eh0 + t * sH, p.wb[1], H, nullptr, nullptr, 0,
          p.xpre + (long)t * 32 * 4 * H, p.bias6[0],
          p.ec[0], p.eh0 + (t + 1) * sH, nullptr, H, 0, 0);
    t = d - 1;
    if (t >= 0 && t < p.S)
      add(p.eh0 + (t + 1) * sH, p.wb[2], H, p.eh1 + t * sH, p.wb[3], H,
          nullptr, p.bias6[1], p.ec[1], p.eh1 + (t + 1) * sH, nullptr,
          H, 0, 1);
    t = d - 2;
    if (t >= 0 && t < p.S)
      add(p.eh1 + (t + 1) * sH, p.wb[4], H, p.eh2 + t * sH, p.wb[5], H,
          nullptr, p.bias6[2], p.ec[2], p.eh2 + (t + 1) * sH, nullptr,
          H, 0, 2);
  } else {
    int d = st - (p.S + 2), t = d;
    if (t < p.FUT) {
      const u16* hprev = (t == 0) ? (p.eh2 + p.S * sH) : (p.dh0 + t * sH);
      add(hprev, p.wb[6], H, nullptr, nullptr, 0,
          nullptr, p.bias6[3], p.dc3[0], p.dh0 + (t + 1) * sH, nullptr,
          H, 1, 0);
    }
    t = d - 1;
    if (t >= 0 && t < p.FUT)
      add(p.dh0 + (t + 1) * sH, p.wb[7], H, p.dh1 + t * sH, p.wb[8], H,
          nullptr, p.bias6[4], p.dc3[1], p.dh1 + (t + 1) * sH, nullptr,
          H, 1, 1);
    t = d - 2;
    if (t >= 0 && t < p.FUT)
      add(p.dh1 + (t + 1) * sH, p.wb[9], H, p.dh2 + t * sD, p.wb[10], D,
          nullptr, p.bias6[5], p.dc3[2], p.dh2 + (t + 1) * sD,
          p.outp + (long)t * 32 * D, D, 0, 2);
  }
  return blk;
}

__device__ void lstm_item(const Cell& cd, int local, void* smemraw, int* swinp) {
  const int nslog = cd.nslog;
  const int nsplit = 1 << nslog;
  const int tile = local >> nslog;
  const int split = local & (nsplit - 1);
  const int g = threadIdx.x >> 6;
  const int lane = threadIdx.x & 63;
  const int colr = lane & 15;
  const int kgrp = lane >> 4;
  const int dh = cd.dh;
  const int dh16 = dh >> 4;
  const int K1 = cd.K1, K2 = cd.K2;

  f32x4 acc0 = {0.f, 0.f, 0.f, 0.f};
  f32x4 acc1 = {0.f, 0.f, 0.f, 0.f};
  const int kbeg = split * cd.chunk;
  const int kend = kbeg + cd.chunk;

  if (kbeg < K1) {
    const int e = kend < K1 ? kend : K1;
    const int ks = K1 >> 5;
    seg_mm((const short8*)cd.A1 + lane,
           (const short8*)cd.W1 + (long)(g * dh16 + tile) * ks * 64 + lane,
           ks, kbeg >> 5, e >> 5, acc0, acc1);
  }
  if (kend > K1 && K2 > 0) {
    const int b0 = kbeg > K1 ? kbeg : K1;
    const int ks = K2 >> 5;
    seg_mm((const short8*)cd.A2 + lane,
           (const short8*)cd.W2 + (long)(g * dh16 + tile) * ks * 64 + lane,
           ks, (b0 - K1) >> 5, (kend - K1) >> 5, acc0, acc1);
  }

  if (nsplit > 1) {
    // split-K partials, plane-major [j][lane]: dense 512B per instruction.
    u64* base = (u64*)(cd.part + ((long)((tile << nslog) + split) * 4 + g) * 512);
    st64coh(base + 0 * 64 + lane, packf2(acc0[0], acc0[1]));
    st64coh(base + 1 * 64 + lane, packf2(acc0[2], acc0[3]));
    st64coh(base + 2 * 64 + lane, packf2(acc1[0], acc1[1]));
    st64coh(base + 3 * 64 + lane, packf2(acc1[2], acc1[3]));
    __threadfence_block();
    __syncthreads();
    if (threadIdx.x == 0)
      *swinp = (atomicAdd(&cd.cnt[tile], 1) == nsplit - 1) ? 1 : 0;
    __syncthreads();
    if (!*swinp) return;
    __threadfence_block();
    for (int os = 0; os < nsplit; ++os) {
      if (os == split) continue;
      const u64* obase = (const u64*)(cd.part + ((long)((tile << nslog) + os) * 4 + g) * 512);
      u64 q0 = ld64coh(obase + 0 * 64 + lane);
      u64 q1 = ld64coh(obase + 1 * 64 + lane);
      u64 q2 = ld64coh(obase + 2 * 64 + lane);
      u64 q3 = ld64coh(obase + 3 * 64 + lane);
      union { u64 u; float f[2]; } t;
      t.u = q0; acc0[0] += t.f[0]; acc0[1] += t.f[1];
      t.u = q1; acc0[2] += t.f[0]; acc0[3] += t.f[1];
      t.u = q2; acc1[0] += t.f[0]; acc1[1] += t.f[1];
      t.u = q3; acc1[2] += t.f[0]; acc1[3] += t.f[1];
    }
    if (threadIdx.x == 0)
      __hip_atomic_store(&cd.cnt[tile], 0, __ATOMIC_RELAXED, __HIP_MEMORY_SCOPE_AGENT);
  }

  float (*ldsG)[16][33] = (float (*)[16][33])smemraw;
#pragma unroll
  for (int j = 0; j < 4; ++j) {
    ldsG[g][colr][kgrp * 4 + j] = acc0[j];
    ldsG[g][colr][16 + kgrp * 4 + j] = acc1[j];
  }
  __syncthreads();

  if (threadIdx.x < 64) {
    const int b2 = threadIdx.x >> 1;
    const int half = threadIdx.x & 1;
    const int u0l = half * 8;
    const int u0 = tile * 16 + u0l;
    // c-state address is reused every stage -> coherent path (small)
    const u64* crd = (const u64*)(cd.cbuf + (long)b2 * dh + u0);
    u64 cw[4];
#pragma unroll
    for (int q = 0; q < 4; ++q) cw[q] = ld64coh(crd + q);
    float hv[8], cv[8], sv[8];
#pragma unroll
    for (int e = 0; e < 8; ++e) {
      int ul = u0l + e;
      int u = tile * 16 + ul;
      float gi = ldsG[0][ul][b2] + cd.bias[u];
      float gf = ldsG[1][ul][b2] + cd.bias[dh + u];
      float gg = ldsG[2][ul][b2] + cd.bias[2 * dh + u];
      float go = ldsG[3][ul][b2] + cd.bias[3 * dh + u];
      if (cd.pre) {
        const float* pb = cd.pre + (long)b2 * 4 * dh;
        gi += pb[u]; gf += pb[dh + u]; gg += pb[2 * dh + u]; go += pb[3 * dh + u];
      }
      union { u64 q; float f[2]; } cu; cu.q = cw[e >> 1];
      float cold = cu.f[e & 1];
      float cn = sigm(gf) * cold + sigm(gi) * tanh_fast(gg);
      cv[e] = cn;
      float h = sigm(go) * tanh_fast(cn);
      hv[e] = h;
      sv[e] = sigm(h);
    }
    u64* cwr = (u64*)(cd.cbuf + (long)b2 * dh + u0);
#pragma unroll
    for (int q = 0; q < 4; ++q)
      st64coh(cwr + q, packf2(cv[2 * q], cv[2 * q + 1]));
    const int ksh = dh >> 5;
    const int mt = b2 >> 4;
    const int kstep = u0 >> 5;
    const int lanep = (b2 & 15) + 16 * ((u0 >> 3) & 3);
    uint4 hp;
    hp.x = pack2bf(hv[0], hv[1]); hp.y = pack2bf(hv[2], hv[3]);
    hp.z = pack2bf(hv[4], hv[5]); hp.w = pack2bf(hv[6], hv[7]);
    // h published via coherent store (L2-bypass); next stage reads it CACHED
    u64* hq = (u64*)&((uint4*)cd.hout)[((long)mt * ksh + kstep) * 64 + lanep];
    st64coh(hq,     (u64)hp.x | ((u64)hp.y << 32));
    st64coh(hq + 1, (u64)hp.z | ((u64)hp.w << 32));
    if (cd.sigout) {
      float4* sp = (float4*)(cd.sigout + (long)b2 * dh + u0);
      sp[0] = make_float4(sv[0], sv[1], sv[2], sv[3]);
      sp[1] = make_float4(sv[4], sv[5], sv[6], sv[7]);
    }
  }
}

__global__ __launch_bounds__(256, 2) void lstm_seq(SeqParams p) {
  __shared__ __align__(16) char smem[16512];   // union: cvt lds (16512B) / ldsG (8448B)
  __shared__ int swin;

  if ((int)blockIdx.x >= p.nlstm) {
    // Dedicated ride blocks: stream ALL decoder-weight conversions with no
    // barrier participation; stream ordering (this dispatch finishes before
    // the decoder dispatch starts) guarantees availability.
    const int nr = (int)gridDim.x - p.nlstm;
    for (int pb = (int)blockIdx.x - p.nlstm; pb < p.rtot; pb += nr) {
      __syncthreads();                 // LDS reuse guard between items
      int r = 0;
      while (pb >= p.rcum[r + 1]) ++r;
      cvt_body(p.rsrc[r], p.rdst[r], pb - p.rcum[r], p.rns[r], p.rklog[r],
               (u16 (*)[1032])smem);
    }
    return;
  }

  int lphase = 0;
  for (int sti = 0; sti < p.nstage; ++sti) {
    const int st = p.stage0 + sti;
    Cell cells[3];
    const int nl = build_stage(p, st, cells);
    for (int it = blockIdx.x; it < nl; it += p.nlstm) {
      __syncthreads();                 // LDS reuse guard between items
      int ci = 0, bstart = 0;
      while (it >= cells[ci].blkend) { bstart = cells[ci].blkend; ++ci; }
      lstm_item(cells[ci], it - bstart, (void*)smem, &swin);
    }
    if (sti + 1 < p.nstage) grid_sync(p.bar, p.nlstm, lphase);
  }
}

// ------------------------------- host -----------------------------------------
extern "C" void kernel_launch(void* const* d_in, const int* in_sizes, int n_in,
                              void* d_out, int out_size, void* d_ws, size_t ws_size,
                              hipStream_t stream)
{
  const float* x_f = (const float*)d_in[0];
  const float* Wih[6]; const float* Whh[6]; const float* bias[6];
  for (int c = 0; c < 6; ++c) {
    Wih[c]  = (const float*)d_in[2 + 3 * c];
    Whh[c]  = (const float*)d_in[3 + 3 * c];
    bias[c] = (const float*)d_in[4 + 3 * c];
  }
  const int H = in_sizes[4] / 4;          // 1024
  const int D = in_sizes[2] / (4 * H);    // 4096
  const int B = 32;
  const int SB = in_sizes[0] / D;         // 640
  const int S = SB / B;                   // 20
  const int FUT = out_size / (B * D);     // 10
  (void)n_in; (void)ws_size;
  int klogH = 31 - __builtin_clz((unsigned)H);
  int klogD = 31 - __builtin_clz((unsigned)D);

  char* wsp = (char*)d_ws;
  size_t off = 0;
  auto alloc = [&](size_t bytes) -> void* {
    off = (off + 255) & ~(size_t)255;
    void* p = (void*)(wsp + off);
    off += bytes;
    return p;
  };

  const float* wsrc[11] = { Wih[0], Whh[0], Wih[1], Whh[1], Wih[2], Whh[2],
                            Whh[3], Wih[4], Whh[4], Wih[5], Whh[5] };
  long welems[11] = { (long)4*H*D, (long)4*H*H, (long)4*H*H, (long)4*H*H,
                      (long)4*H*H, (long)4*H*H, (long)4*H*H, (long)4*H*H,
                      (long)4*H*H, (long)4*D*H, (long)4*D*(long)D };
  int wrows[11] = { 4*H, 4*H, 4*H, 4*H, 4*H, 4*H, 4*H, 4*H, 4*H, 4*D, 4*D };
  int wklog[11] = { klogD, klogH, klogH, klogH, klogH, klogH,
                    klogH, klogH, klogH, klogH, klogD };
  u16* wb[11];
  for (int i = 0; i < 11; ++i) wb[i] = (u16*)alloc((size_t)welems[i] * 2);
  u16* xbf = (u16*)alloc((size_t)SB * D * 2);
  float* xpre = (float*)alloc((size_t)SB * D * 4);

  size_t zbeg = (off + 255) & ~(size_t)255;
  int* cnt = (int*)alloc(3 * 256 * 4);
  int* gbar = (int*)alloc(16384);         // two independent barrier trees
  const long sH = (long)B * H;            // u16 elems per h slot
  const long sD = (long)B * D;
  u16* eh0 = (u16*)alloc((size_t)(S + 1) * sH * 2);
  u16* eh1 = (u16*)alloc((size_t)(S + 1) * sH * 2);
  u16* eh2 = (u16*)alloc((size_t)(S + 1) * sH * 2);
  u16* dh0 = (u16*)alloc((size_t)(FUT + 1) * sH * 2);
  u16* dh1 = (u16*)alloc((size_t)(FUT + 1) * sH * 2);
  u16* dh2 = (u16*)alloc((size_t)(FUT + 1) * sD * 2);
  float* ec[3]; float* dc[3];
  for (int c = 0; c < 3; ++c) ec[c] = (float*)alloc((size_t)B * H * 4);
  dc[0] = (float*)alloc((size_t)B * H * 4);
  dc[1] = (float*)alloc((size_t)B * H * 4);
  dc[2] = (float*)alloc((size_t)B * D * 4);
  size_t zend = off;

  const long PARTSTRIDE = (long)256 * 8 * 4 * 512;   // floats per cell slot region
  float* part = (float*)alloc((size_t)3 * PARTSTRIDE * 4);

  hipMemsetAsync((void*)(wsp + zbeg), 0, zend - zbeg, stream);

  // ---- upfront conversion: encoder weights (wsrc[0..5]) + x ----
  PKArgs pa;
  int cum = 0;
  for (int i = 0; i < 7; ++i) {
    int rows, klog;
    if (i < 6) { rows = wrows[i]; klog = wklog[i]; pa.src[i] = wsrc[i]; pa.dst[i] = (uint4*)wb[i]; }
    else       { rows = SB;       klog = klogD;    pa.src[i] = x_f;     pa.dst[i] = (uint4*)xbf; }
    int ns = 1 << (klog - 10);
    pa.cum[i] = cum;
    pa.nspan[i] = ns;
    pa.klog[i] = klog;
    cum += (rows / 8) * ns;
  }
  for (int i = 7; i <= NPK; ++i) pa.cum[i] = cum;
  cvt_pack<<<dim3(cum), dim3(256), 0, stream>>>(pa);

  gemm_pre<<<dim3(SB / 64, (4 * H) / 64), dim3(256), 0, stream>>>(xbf, wb[0], xpre, 4 * H, D);

  // ---- persistent sequence kernels: encoder (+dedicated ride blocks), decoder ----
  SeqParams sp;
  for (int i = 0; i < 11; ++i) sp.wb[i] = wb[i];
  for (int i = 0; i < 6; ++i) sp.bias6[i] = bias[i];
  sp.eh0 = eh0; sp.eh1 = eh1; sp.eh2 = eh2;
  sp.dh0 = dh0; sp.dh1 = dh1; sp.dh2 = dh2;
  for (int c = 0; c < 3; ++c) { sp.ec[c] = ec[c]; sp.dc3[c] = dc[c]; }
  sp.xpre = xpre; sp.part = part; sp.cnt = cnt;
  sp.outp = (float*)d_out;
  sp.S = S; sp.FUT = FUT; sp.H = H; sp.D = D;
  int rcum = 0;
  for (int i = 0; i < 5; ++i) {
    int wi = 6 + i;
    sp.rsrc[i] = wsrc[wi];
    sp.rdst[i] = (uint4*)wb[wi];
    int ns = 1 << (wklog[wi] - 10);
    sp.rcum[i] = rcum;
    sp.rns[i] = ns;
    sp.rklog[i] = wklog[wi];
    rcum += (wrows[wi] / 8) * ns;
  }
  sp.rcum[5] = rcum;
  sp.rtot = rcum;

  // encoder dispatch: LSTM barrier group = blocks 0..255; ride blocks 256..511
  sp.stage0 = 0;
  sp.nstage = S + 2;
  sp.nlstm = 256;
  sp.bar = gbar;
  lstm_seq<<<dim3(512), dim3(256), 0, stream>>>(sp);

  // decoder dispatch: all 512 blocks in the barrier group, no rides.
  // Kernel boundary publishes ride-converted weights to all XCDs.
  sp.stage0 = S + 2;
  sp.nstage = FUT + 2;
  sp.nlstm = 512;
  sp.rtot = 0;
  sp.bar = gbar + 2048;
  lstm_seq<<<dim3(512), dim3(256), 0, stream>>>(sp);
}